// Round 12
// baseline (277.246 us; speedup 1.0000x reference)
//
#include <hip/hip_runtime.h>
#include <hip/hip_bf16.h>
#include <cstdint>
#include <cstdio>

#define EMB    1024
#define HEADS  16
#define HD     64
#define TSEQ   2048
#define NBATCH 4
#define BT     (NBATCH*TSEQ)   // 8192
#define QKVN   3072            // fused QKV GEMM output width
#define QKLD   2048            // Q,K buffer row stride

// log2(e) / sqrt(2048) — folded into Wq/bq at cast time
#define CSCALE (1.4426950408889634f * 0.022097086912079608f)

typedef __hip_bfloat16 bf16;
typedef __attribute__((ext_vector_type(8))) short short8;   // 8 bf16 (K=32 MFMA A/B frag)
typedef __attribute__((ext_vector_type(4))) short short4v;  // 4 bf16 (K=16 MFMA A/B frag)
typedef __attribute__((ext_vector_type(4))) float f32x4;    // MFMA C/D frag

#define MFMA32(A,B,C) __builtin_amdgcn_mfma_f32_16x16x32_bf16(A,B,C,0,0,0)
#if __has_builtin(__builtin_amdgcn_mfma_f32_16x16x16_bf16)
#define MFMA16(A,B,C) __builtin_amdgcn_mfma_f32_16x16x16_bf16(A,B,C,0,0,0)
#else
#define MFMA16(A,B,C) __builtin_amdgcn_mfma_f32_16x16x16bf16_1k(A,B,C,0,0,0)
#endif

#if __has_builtin(__builtin_amdgcn_exp2f)
#define EXP2(x) __builtin_amdgcn_exp2f(x)
#else
#define EXP2(x) exp2f(x)
#endif

template<bool B> struct BoolC { static constexpr bool value = B; };

__device__ __forceinline__ void gload_lds16(const void* g, void* l) {
  __builtin_amdgcn_global_load_lds(
      (const __attribute__((address_space(1))) void*)g,
      (__attribute__((address_space(3))) void*)l,
      16, 0, 0);
}

// pack 2 floats -> 2 bf16 (round-half-up) in one v_perm
__device__ __forceinline__ unsigned pkbf(float a, float b) {
  unsigned ua = __builtin_bit_cast(unsigned, a) + 0x8000u;
  unsigned ub = __builtin_bit_cast(unsigned, b) + 0x8000u;
  return __builtin_amdgcn_perm(ub, ua, 0x07060302u);  // {a.hi16, b.hi16}
}

// raw barriers with compiler memory fences (NOT __syncthreads: that drains vmcnt(0))
#define BARRIER() do { asm volatile("" ::: "memory"); \
                       __builtin_amdgcn_s_barrier(); \
                       asm volatile("" ::: "memory"); } while (0)
#define BAR_VM(N) do { asm volatile("s_waitcnt vmcnt(" #N ")" ::: "memory"); \
                       __builtin_amdgcn_s_barrier(); \
                       asm volatile("" ::: "memory"); } while (0)

// ---------------------------------------------------------------------------
// One launch: cast x -> xb, {Wq*CSCALE,Wk,Wv} -> wqkv, Wp -> wpb,
// concat {bq*CSCALE,bk,bv} -> biasqkv (f32).
// ---------------------------------------------------------------------------
__global__ void fused_cast(const float* __restrict__ x, const float* __restrict__ Wq,
                           const float* __restrict__ Wk, const float* __restrict__ Wv,
                           const float* __restrict__ Wp, const float* __restrict__ bq,
                           const float* __restrict__ bk, const float* __restrict__ bv,
                           bf16* __restrict__ xb, bf16* __restrict__ wqkv,
                           bf16* __restrict__ wpb, float* __restrict__ biasqkv) {
  const int blk = blockIdx.x;
  const int i = threadIdx.x * 4;
  if (blk >= 12288) {
    const int wsel = blk - 12288;
    const float* bsrc = wsel == 0 ? bq : (wsel == 1 ? bk : bv);
    float4 bv4 = *(const float4*)(bsrc + i);
    if (wsel == 0) { bv4.x *= CSCALE; bv4.y *= CSCALE; bv4.z *= CSCALE; bv4.w *= CSCALE; }
    *(float4*)(biasqkv + wsel * 1024 + i) = bv4;
    return;
  }
  const float* src; bf16* dst; float sc = 1.0f;
  if (blk < 8192)       { src = x  + (size_t)blk * 1024;           dst = xb   + (size_t)blk * 1024; }
  else if (blk < 9216)  { src = Wq + (size_t)(blk - 8192) * 1024;  dst = wqkv + (size_t)(blk - 8192) * 1024; sc = CSCALE; }
  else if (blk < 10240) { src = Wk + (size_t)(blk - 9216) * 1024;  dst = wqkv + ((size_t)1 << 20) + (size_t)(blk - 9216) * 1024; }
  else if (blk < 11264) { src = Wv + (size_t)(blk - 10240) * 1024; dst = wqkv + ((size_t)2 << 20) + (size_t)(blk - 10240) * 1024; }
  else                  { src = Wp + (size_t)(blk - 11264) * 1024; dst = wpb  + (size_t)(blk - 11264) * 1024; }
  float4 v = *(const float4*)(src + i);
  union { short4v v; bf16 b[4]; } u;
  u.b[0] = __float2bfloat16(v.x * sc); u.b[1] = __float2bfloat16(v.y * sc);
  u.b[2] = __float2bfloat16(v.z * sc); u.b[3] = __float2bfloat16(v.w * sc);
  *(short4v*)(dst + i) = u.v;
}

// ---------------------------------------------------------------------------
// 8-phase 256x128-tile GEMM machinery (T2+T3+T4+T5), C = A @ B^T + bias.
// 512 thr = 8 waves (2M x 4N); per-wave 128x32 out (acc[8][2]); BK=64;
// LDS 96KiB (A 2x32K | B 2x16K). Counted vmcnt: issue B -> A.j0 -> A.j1
// (6 loads/tile), BAR_VM(4) @P2-end, BAR_VM(2) @P4-end. Used by BOTH the
// projection GEMM (f32 out, 256 blocks) and the QKV GEMM (bf16 qk + vt
// transpose out, 768 blocks = exactly 3 balanced rounds at 1 block/CU —
// replaces the 256x256/384-block version whose 1.5-round grid wasted 25%).
// ---------------------------------------------------------------------------
#define PJ_MFMA(MI0) do { \
  __builtin_amdgcn_s_setprio(1); \
  _Pragma("unroll") \
  for (int m2 = 0; m2 < 2; ++m2) { \
    _Pragma("unroll") \
    for (int nj = 0; nj < 2; ++nj) { \
      acc[(MI0)+m2][nj] = MFMA32(af[m2][0], bfr[nj][0], acc[(MI0)+m2][nj]); \
      acc[(MI0)+m2][nj] = MFMA32(af[m2][1], bfr[nj][1], acc[(MI0)+m2][nj]); \
    } \
  } \
  __builtin_amdgcn_s_setprio(0); \
} while (0)

#define PJ_TILE(T, P) { \
  const int kn = ((T) + 1) * 64; \
  const bool st = (T) < 15; \
  const char* aB = rdA + (P) * 32768; \
  const char* bB = rdB + (P) * 16384; \
  char* sA = ldsA + ((P) ^ 1) * 32768 + wbase; \
  char* sB = ldsB + ((P) ^ 1) * 16384 + wbase; \
  /* ---- P1: mi 0-1; all bfr ---- */ \
  _Pragma("unroll") \
  for (int m2 = 0; m2 < 2; ++m2) { \
    af[m2][0] = *(const short8*)(aB + m2 * 2048 + cs0); \
    af[m2][1] = *(const short8*)(aB + m2 * 2048 + cs1); \
  } \
  _Pragma("unroll") \
  for (int nj = 0; nj < 2; ++nj) { \
    bfr[nj][0] = *(const short8*)(bB + nj * 2048 + cs0); \
    bfr[nj][1] = *(const short8*)(bB + nj * 2048 + cs1); \
  } \
  if (st) { gload_lds16(gB + kn,         sB); \
            gload_lds16(gB + 65536 + kn, sB + 8192); } \
  BARRIER(); \
  PJ_MFMA(0); \
  BARRIER(); \
  /* ---- P2: mi 2-3 ---- */ \
  _Pragma("unroll") \
  for (int m2 = 0; m2 < 2; ++m2) { \
    af[m2][0] = *(const short8*)(aB + (2 + m2) * 2048 + cs0); \
    af[m2][1] = *(const short8*)(aB + (2 + m2) * 2048 + cs1); \
  } \
  if (st) { gload_lds16(gA + kn,          sA); \
            gload_lds16(gA + 131072 + kn, sA + 16384); } \
  BARRIER(); \
  PJ_MFMA(2); \
  if (st) { BAR_VM(4); } else { BAR_VM(0); } \
  /* ---- P3: mi 4-5 ---- */ \
  _Pragma("unroll") \
  for (int m2 = 0; m2 < 2; ++m2) { \
    af[m2][0] = *(const short8*)(aB + (4 + m2) * 2048 + cs0); \
    af[m2][1] = *(const short8*)(aB + (4 + m2) * 2048 + cs1); \
  } \
  if (st) { gload_lds16(gA + 65536 + kn,  sA + 8192); \
            gload_lds16(gA + 196608 + kn, sA + 24576); } \
  BARRIER(); \
  PJ_MFMA(4); \
  BARRIER(); \
  /* ---- P4: mi 6-7 ---- */ \
  _Pragma("unroll") \
  for (int m2 = 0; m2 < 2; ++m2) { \
    af[m2][0] = *(const short8*)(aB + (6 + m2) * 2048 + cs0); \
    af[m2][1] = *(const short8*)(aB + (6 + m2) * 2048 + cs1); \
  } \
  PJ_MFMA(6); \
  if (st) { BAR_VM(2); } \
}

// common body prefix: decode ids, build staging/read pointers, run K loop
#define PJ_BODY(GRID_DECODE) \
  __shared__ short smem[49152]; \
  const int tid = threadIdx.x; \
  const int l = tid & 63, w = tid >> 6; \
  const int r = l & 15, qd = l >> 4; \
  const int wm = w >> 2, wn = w & 3; \
  GRID_DECODE \
  const int rowA = tid >> 3; \
  const int chk = (tid & 7) ^ (rowA & 7); \
  const bf16* gA = A + (size_t)(m0 + rowA) * 1024 + chk * 8; \
  const bf16* gB = B + (size_t)(n0 + rowA) * 1024 + chk * 8; \
  char* ldsA = (char*)smem; \
  char* ldsB = (char*)smem + 65536; \
  const int wbase = w * 1024; \
  const char* rdA = (const char*)smem + wm * 16384 + r * 128; \
  const char* rdB = (const char*)smem + 65536 + (wn * 32 + r) * 128; \
  const int cs0 = (qd ^ (r & 7)) * 16; \
  const int cs1 = ((4 + qd) ^ (r & 7)) * 16; \
  f32x4 acc[8][2]; \
  _Pragma("unroll") \
  for (int i = 0; i < 8; ++i) \
    _Pragma("unroll") \
    for (int j = 0; j < 2; ++j) acc[i][j] = (f32x4){0.f, 0.f, 0.f, 0.f}; \
  short8 af[2][2], bfr[2][2]; \
  { \
    char* sA = ldsA + wbase; \
    char* sB = ldsB + wbase; \
    gload_lds16(gB,          sB); \
    gload_lds16(gB + 65536,  sB + 8192); \
    gload_lds16(gA,          sA); \
    gload_lds16(gA + 131072, sA + 16384); \
    gload_lds16(gA + 65536,  sA + 8192); \
    gload_lds16(gA + 196608, sA + 24576); \
    BAR_VM(2); \
  } \
  _Pragma("unroll 1") \
  for (int tt = 0; tt < 8; ++tt) { \
    PJ_TILE(tt * 2, 0) \
    PJ_TILE(tt * 2 + 1, 1) \
  }

// ---------------------------------------------------------------------------
// QKV GEMM: C[8192,3072] = xb @ wqkv^T + bias. 768 blocks (32m x 24n),
// bijective XCD swizzle (96/XCD). Epilogue: n0<2048 -> bf16 qk direct
// stores; n0>=2048 -> vt LDS-transpose (128-col image, 64KiB).
// ---------------------------------------------------------------------------
__global__ __launch_bounds__(512, 2) void gemm_qkv12(
    const bf16* __restrict__ A, const bf16* __restrict__ B,
    const float* __restrict__ bias, bf16* __restrict__ qkout,
    bf16* __restrict__ vt) {
  PJ_BODY(
    const int f0 = blockIdx.x;
    const int sid = (f0 & 7) * 96 + (f0 >> 3);
    const int m0 = (sid / 24) * 256;
    const int n0 = (sid % 24) * 128;
  )

  if (n0 < 2048) {
    // ---- qk epilogue: direct bf16 stores (16 lanes -> 32B pieces) ----
#pragma unroll
    for (int nj = 0; nj < 2; ++nj) {
      const int col = n0 + wn * 32 + nj * 16 + r;
      const float bv = bias[col];
#pragma unroll
      for (int mi = 0; mi < 8; ++mi) {
#pragma unroll
        for (int reg = 0; reg < 4; ++reg) {
          const int row = m0 + wm * 128 + mi * 16 + qd * 4 + reg;
          qkout[(size_t)row * QKLD + col] = __float2bfloat16(acc[mi][nj][reg] + bv);
        }
      }
    }
  } else {
    // ---- vt epilogue: LDS transpose to exact vt memory image ----
    // image: 128 rows (c_local -> (h,d)) x 512B (swizzled 256-t chunk) = 64KiB.
    __syncthreads();   // PJ_TILE P4 ds_reads (post-last-barrier) must finish
    char* img = (char*)smem;
#pragma unroll
    for (int nj = 0; nj < 2; ++nj) {
      const int c_local = wn * 32 + nj * 16 + r;
      const float bv = bias[n0 + c_local];
      const int d7 = c_local & 7;
#pragma unroll
      for (int mi = 0; mi < 8; ++mi) {
        const int tbase = wm * 128 + mi * 16 + qd * 4;   // t_local of reg 0
        const int chunk = tbase >> 6;                    // 64-t chunk (128B)
        const int sbits = ((tbase >> 3) ^ d7) & 7;       // flash swizzle bits
        union { short4v v; bf16 b[4]; } u;
#pragma unroll
        for (int reg = 0; reg < 4; ++reg)
          u.b[reg] = __float2bfloat16(acc[mi][nj][reg] + bv);
        *(short4v*)(img + c_local * 512 + chunk * 128 + sbits * 16 + (qd & 1) * 8) = u.v;
      }
    }
    __syncthreads();   // ds_writes visible to all waves
    // coalesced read-back: 32 lanes per 512B row segment, 8 iterations
    const int bb = m0 >> 11, tb = m0 & 2047;
    const int hb = (n0 - 2048) >> 6;
    const int off = (tid & 31) * 16;
#pragma unroll
    for (int i = 0; i < 8; ++i) {
      const int row = i * 16 + (tid >> 5);               // 0..127
      const int h2 = hb + (row >> 6), d = row & 63;
      const f32x4 vv = *(const f32x4*)(img + row * 512 + off);
      char* dst = (char*)(vt + ((size_t)(bb * 16 + h2) * 64 + d) * 2048 + tb) + off;
      *(f32x4*)dst = vv;
    }
  }
}

// ---------------------------------------------------------------------------
// Projection GEMM: C[8192,1024] = pb @ wpb^T + bias, f32 out. 256 blocks
// (32m x 8n, 32/XCD), exactly 1 round. Unchanged from round 8 (verified).
// ---------------------------------------------------------------------------
__global__ __launch_bounds__(512, 2) void gemm_proj8(
    const bf16* __restrict__ A, const bf16* __restrict__ B,
    const float* __restrict__ bias, float* __restrict__ out) {
  PJ_BODY(
    const int f0 = blockIdx.x;
    const int sid = (f0 & 7) * 32 + (f0 >> 3);
    const int m0 = (sid >> 3) * 256;
    const int n0 = (sid & 7) * 128;
  )

  // epilogue: f32 direct stores
#pragma unroll
  for (int nj = 0; nj < 2; ++nj) {
    const int col = n0 + wn * 32 + nj * 16 + r;
    const float bv = bias[col];
#pragma unroll
    for (int mi = 0; mi < 8; ++mi) {
#pragma unroll
      for (int reg = 0; reg < 4; ++reg) {
        const int row = m0 + wm * 128 + mi * 16 + qd * 4 + reg;
        out[(size_t)row * 1024 + col] = acc[mi][nj][reg] + bv;
      }
    }
  }
}

// ---------------------------------------------------------------------------
// Causal flash attention v9b (round 11, verified): kt-parity split across 2
// wave-groups, all-LDS-ring staging (V+K, 4-deep, post-barrier issue),
// launch_bounds(512,2) — 112 VGPR, no spill. 78.2us measured.
// ---------------------------------------------------------------------------
__global__ __launch_bounds__(512, 2) void flash9(
    const bf16* __restrict__ qk, const bf16* __restrict__ vt,
    const float* __restrict__ x, bf16* __restrict__ pb) {
  const int bh = blockIdx.x;            // 0..63 -> XCD = bh%8
  const int ip = blockIdx.y;            // 0..7
  const int b = bh >> 4, h = bh & 15;
  const int qt[4] = { 31 - ip, 23 - ip, ip + 8, ip };   // descending
  const int tid = threadIdx.x, l = tid & 63, w = tid >> 6;
  const int wg = w & 3, grp = w >> 2;   // wg: q-row group; grp: kt parity
  const int r = l & 15, quad = l >> 4;

  __shared__ __align__(16) char smem[65536];  // V ring [4][8K] | K ring [4][8K] @32K

  const bf16* Qbase = qk + (size_t)b * TSEQ * QKLD + h * HD;
  const bf16* Kbase = Qbase + 1024;
  const bf16* Vhead = vt + (size_t)bh * 64 * 2048;

  // V staging: slot tid -> d=tid>>3, chunk tid&7 (vt image rows verbatim)
  const bf16* vg = Vhead + (size_t)(tid >> 3) * 2048 + (tid & 7) * 8;
  // K staging: dest row=tid>>3, phys chunk tid&7 holds global chunk ^(row&7)
  const int krow = tid >> 3;
  const bf16* kg = Kbase + (size_t)krow * QKLD + ((tid & 7) ^ (krow & 7)) * 8;
  char* vbase = smem + w * 1024;              // + (kt&3)*8192
  char* kbase = smem + 32768 + w * 1024;      // + (kt&3)*8192

  // Q fragments (B-operand of S^T: n=lane&15=qrow, k=quad*8+j)
  short8 qf0[4], qf1[4];
#pragma unroll
  for (int t = 0; t < 4; ++t) {
    const bf16* qp = Qbase + (size_t)(qt[t] * 64 + wg * 16 + r) * QKLD + quad * 8;
    qf0[t] = *(const short8*)qp;
    qf1[t] = *(const short8*)(qp + 32);
  }

  f32x4 o[4][4], lac[4];
#pragma unroll
  for (int t = 0; t < 4; ++t) {
    lac[t] = (f32x4){0.f, 0.f, 0.f, 0.f};
#pragma unroll
    for (int nt = 0; nt < 4; ++nt) o[t][nt] = (f32x4){0.f, 0.f, 0.f, 0.f};
  }

  short4v ones4;
#pragma unroll
  for (int j = 0; j < 4; ++j) ones4[j] = (short)0x3F80;  // bf16 1.0

  short4v vf[4][4];

  const int ktmax = qt[0];
  const int qrow_l = wg * 16 + r;

  // prologue: stage V(0),V(1),K(0),K(1) into ring slots 0,1
  gload_lds16(vg,           vbase);
  gload_lds16(vg + 64,      vbase + 8192);
  gload_lds16(kg,           kbase);
  gload_lds16(kg + 131072,  kbase + 8192);    // kt stride = 64*QKLD elems

  auto tilestep = [&](int t, auto diagc, short8 (&k0)[4], short8 (&k1)[4]) {
    constexpr bool D = decltype(diagc)::value;
    f32x4 s[4];
    __builtin_amdgcn_s_setprio(1);
#pragma unroll
    for (int g = 0; g < 4; ++g) {
      f32x4 a = (f32x4){0.f, 0.f, 0.f, 0.f};
      a = MFMA32(k0[g], qf0[t], a);     // A=K, B=Q -> S^T[key][q]
      a = MFMA32(k1[g], qf1[t], a);
      s[g] = a;
    }
    __builtin_amdgcn_s_setprio(0);
    short4v pA[4];
#pragma unroll
    for (int g = 0; g < 4; ++g) {
      float p[4];
#pragma unroll
      for (int reg = 0; reg < 4; ++reg) {
        float e = EXP2(s[g][reg]);      // scale pre-folded into Q
        if (D) {
          const int kj = g * 16 + quad * 4 + reg;   // key local (kt==qt)
          if (kj > qrow_l) e = 0.f;
        }
        p[reg] = e;
      }
      union { short4v v; unsigned u[2]; } pu;
      pu.u[0] = pkbf(p[0], p[1]);
      pu.u[1] = pkbf(p[2], p[3]);
      pA[g] = pu.v;
    }
    __builtin_amdgcn_s_setprio(1);
#pragma unroll
    for (int nt = 0; nt < 4; ++nt)
#pragma unroll
      for (int g = 0; g < 4; ++g)
        o[t][nt] = MFMA16(pA[g], vf[nt][g], o[t][nt]);
#pragma unroll
    for (int g = 0; g < 4; ++g)
      lac[t] = MFMA16(pA[g], ones4, lac[t]);
    __builtin_amdgcn_s_setprio(0);
  };

  const int niter = (ktmax >> 1) + 1;
#pragma unroll 1
  for (int i = 0; i < niter; ++i) {
    const int kt = 2 * i + grp;
    const bool act = kt <= ktmax;       // group-uniform (whole waves)
    __syncthreads();                    // prev-iteration stages landed (covered)
    // prefetch next pair (tiles 2i+2, 2i+3) into slots freed at iter i-1
    const int nx0 = 2 * i + 2, nx1 = 2 * i + 3;
    if (nx0 <= ktmax) {
      gload_lds16(vg + nx0 * 64,            smem + (nx0 & 3) * 8192 + w * 1024);
      gload_lds16(kg + (size_t)nx0 * 131072, smem + 32768 + (nx0 & 3) * 8192 + w * 1024);
    }
    if (nx1 <= ktmax) {
      gload_lds16(vg + nx1 * 64,            smem + (nx1 & 3) * 8192 + w * 1024);
      gload_lds16(kg + (size_t)nx1 * 131072, smem + 32768 + (nx1 & 3) * 8192 + w * 1024);
    }
    if (act) {
      // K frags from LDS ring (XOR-swizzle read; row&7 == r&7 since g*16%8==0)
      short8 k0[4], k1[4];
      {
        const bf16* Kt = (const bf16*)(smem + 32768 + (kt & 3) * 8192);
#pragma unroll
        for (int g = 0; g < 4; ++g) {
          const bf16* kp = Kt + (g * 16 + r) * 64;
          k0[g] = *(const short8*)(kp + ((quad ^ (r & 7)) * 8));
          k1[g] = *(const short8*)(kp + (((quad + 4) ^ (r & 7)) * 8));
        }
      }
      {
        const bf16* V = (const bf16*)smem + (kt & 3) * 4096;
#pragma unroll
        for (int nt = 0; nt < 4; ++nt)
#pragma unroll
          for (int g = 0; g < 4; ++g)
            vf[nt][g] = *(const short4v*)(V + (nt * 16 + r) * 64 +
                                          (((g * 2 + (quad >> 1)) ^ (r & 7)) * 8) + (quad & 1) * 4);
      }
      if (kt == qt[0]) tilestep(0, BoolC<true>{}, k0, k1);
      else             tilestep(0, BoolC<false>{}, k0, k1);
      if (kt <= qt[1]) { if (kt == qt[1]) tilestep(1, BoolC<true>{}, k0, k1);
                         else             tilestep(1, BoolC<false>{}, k0, k1); }
      if (kt <= qt[2]) { if (kt == qt[2]) tilestep(2, BoolC<true>{}, k0, k1);
                         else             tilestep(2, BoolC<false>{}, k0, k1); }
      if (kt <= qt[3]) { if (kt == qt[3]) tilestep(3, BoolC<true>{}, k0, k1);
                         else             tilestep(3, BoolC<false>{}, k0, k1); }
    }
  }

  // ---- combine (2 rounds) + split epilogue (reuses smem[0..40K)) ----
  float* combO = (float*)smem;                 // 32 KB: [wg*64+l][8 chunks x 16B]
  float* combL = (float*)(smem + 32768);       // 8 KB : [wg*64+l][2 tiles x 16B]
  const int lb128 = (wg * 64 + l) * 32;        // float index of lane's 128B block
  const int lbl = (wg * 64 + l) * 8;

  __syncthreads();                             // all ring reads + stages complete
#pragma unroll
  for (int rnd = 0; rnd < 2; ++rnd) {
    const int wgrp = (rnd == 0) ? 1 : 0;       // writer group this round
    if (grp == wgrp) {
#pragma unroll
      for (int t2 = 0; t2 < 2; ++t2) {
        const int tt = rnd * 2 + t2;
#pragma unroll
        for (int nt = 0; nt < 4; ++nt)
          *(f32x4*)&combO[lb128 + (((t2 * 4 + nt) ^ (l & 7)) << 2)] = o[tt][nt];
        *(f32x4*)&combL[lbl + t2 * 4] = lac[tt];
      }
    }
    __syncthreads();
    if (grp != wgrp) {
#pragma unroll
      for (int t2 = 0; t2 < 2; ++t2) {
        const int tt = rnd * 2 + t2;
        const f32x4 ls = *(const f32x4*)&combL[lbl + t2 * 4];
#pragma unroll
        for (int j2 = 0; j2 < 4; ++j2) lac[tt][j2] += ls[j2];
#pragma unroll
        for (int nt = 0; nt < 4; ++nt) {
          const f32x4 ov = *(const f32x4*)&combO[lb128 + (((t2 * 4 + nt) ^ (l & 7)) << 2)];
#pragma unroll
          for (int j2 = 0; j2 < 4; ++j2) o[tt][nt][j2] += ov[j2];
        }
        // epilogue for tile tt: O /= l, +residual, bf16 store
#pragma unroll
        for (int reg = 0; reg < 4; ++reg) {
          const float inv = 1.0f / lac[tt][reg];
          const int row = qt[tt] * 64 + wg * 16 + quad * 4 + reg;
          const float* xr = x + (size_t)(b * TSEQ + row) * EMB + h * HD;
          bf16* pr = pb + (size_t)(b * TSEQ + row) * EMB + h * HD;
#pragma unroll
          for (int nt = 0; nt < 4; ++nt) {
            const int d = nt * 16 + r;
            pr[d] = __float2bfloat16(o[tt][nt][reg] * inv + xr[d]);
          }
        }
      }
    }
    if (rnd == 0) __syncthreads();             // round-1 reads done before round-2 writes
  }
}

// ---------------------------------------------------------------------------
// In-place LayerNorm over last dim (1024). One block per row, 256 thr x 4.
// ---------------------------------------------------------------------------
__global__ __launch_bounds__(256) void ln_kernel(float* __restrict__ out,
                                                 const float* __restrict__ gamma,
                                                 const float* __restrict__ beta) {
  const int row = blockIdx.x;
  const int tid = threadIdx.x;
  float* p = out + (size_t)row * EMB;
  float4 v = ((const float4*)p)[tid];
  float s = v.x + v.y + v.z + v.w;
  float ss = v.x * v.x + v.y * v.y + v.z * v.z + v.w * v.w;
#pragma unroll
  for (int m = 1; m < 64; m <<= 1) {
    s += __shfl_xor(s, m, 64);
    ss += __shfl_xor(ss, m, 64);
  }
  __shared__ float red[8];
  const int w = tid >> 6, l = tid & 63;
  if (l == 0) { red[w] = s; red[4 + w] = ss; }
  __syncthreads();
  s = red[0] + red[1] + red[2] + red[3];
  ss = red[4] + red[5] + red[6] + red[7];
  const float mu = s * (1.0f / EMB);
  const float var = ss * (1.0f / EMB) - mu * mu;
  const float rs = rsqrtf(var + 1e-6f);
  const float4 g = ((const float4*)gamma)[tid];
  const float4 bb = ((const float4*)beta)[tid];
  float4 o;
  o.x = (v.x - mu) * rs * g.x + bb.x;
  o.y = (v.y - mu) * rs * g.y + bb.y;
  o.z = (v.z - mu) * rs * g.z + bb.z;
  o.w = (v.w - mu) * rs * g.w + bb.w;
  ((float4*)p)[tid] = o;
}

// ---------------------------------------------------------------------------
extern "C" void kernel_launch(void* const* d_in, const int* in_sizes, int n_in,
                              void* d_out, int out_size, void* d_ws, size_t ws_size,
                              hipStream_t stream) {
  const float* x     = (const float*)d_in[0];
  const float* Wq    = (const float*)d_in[1];
  const float* bq    = (const float*)d_in[2];
  const float* Wk    = (const float*)d_in[3];
  const float* bk    = (const float*)d_in[4];
  const float* Wv    = (const float*)d_in[5];
  const float* bv    = (const float*)d_in[6];
  const float* Wp    = (const float*)d_in[7];
  const float* bp    = (const float*)d_in[8];
  const float* gamma = (const float*)d_in[9];
  const float* beta  = (const float*)d_in[10];
  float* out = (float*)d_out;

  // ws: xb 0-16M (reused as pb), wqkv 16-22M, wpb 22-24M, bqkv 24M(+12KB),
  // qk 25-57M (stride 2048), vt 57-73M ([b][h][d][T] swizzled)
  if (ws_size < (size_t)74 * 1024 * 1024) {
    printf("kernel_launch: ws_size %zu too small\n", ws_size);
    return;
  }
  char* ws = (char*)d_ws;
  bf16* xb    = (bf16*)ws;
  bf16* wqkv  = (bf16*)(ws + ((size_t)16 << 20));
  bf16* wpb   = (bf16*)(ws + ((size_t)22 << 20));
  float* bqkv = (float*)(ws + ((size_t)24 << 20));
  bf16* qkbuf = (bf16*)(ws + ((size_t)25 << 20));
  bf16* vtbuf = (bf16*)(ws + ((size_t)57 << 20));
  bf16* pbuf  = xb;  // xb dead after QKV GEMM

  fused_cast<<<12291, 256, 0, stream>>>(x, Wq, Wk, Wv, Wp, bq, bk, bv, xb, wqkv, wpb, bqkv);

  gemm_qkv12<<<dim3(768), dim3(512), 0, stream>>>(xb, wqkv, bqkv, qkbuf, vtbuf);

  flash9<<<dim3(64, 8), 512, 0, stream>>>(qkbuf, vtbuf, x, pbuf);

  gemm_proj8<<<dim3(256), dim3(512), 0, stream>>>(pbuf, wpb, bp, out);

  ln_kernel<<<BT, 256, 0, stream>>>(out, gamma, beta);
}

// Round 14
// 276.360 us; speedup vs baseline: 1.0032x; 1.0032x over previous
//
#include <hip/hip_runtime.h>
#include <hip/hip_bf16.h>
#include <cstdint>
#include <cstdio>

#define EMB    1024
#define HEADS  16
#define HD     64
#define TSEQ   2048
#define NBATCH 4
#define BT     (NBATCH*TSEQ)   // 8192
#define QKVN   3072            // fused QKV GEMM output width
#define QKLD   2048            // Q,K buffer row stride

// log2(e) / sqrt(2048) — folded into Wq/bq at cast time
#define CSCALE (1.4426950408889634f * 0.022097086912079608f)

typedef __hip_bfloat16 bf16;
typedef __attribute__((ext_vector_type(8))) short short8;   // 8 bf16 (K=32 MFMA A/B frag)
typedef __attribute__((ext_vector_type(4))) short short4v;  // 4 bf16 (K=16 MFMA A/B frag)
typedef __attribute__((ext_vector_type(4))) float f32x4;    // MFMA C/D frag

#define MFMA32(A,B,C) __builtin_amdgcn_mfma_f32_16x16x32_bf16(A,B,C,0,0,0)
#if __has_builtin(__builtin_amdgcn_mfma_f32_16x16x16_bf16)
#define MFMA16(A,B,C) __builtin_amdgcn_mfma_f32_16x16x16_bf16(A,B,C,0,0,0)
#else
#define MFMA16(A,B,C) __builtin_amdgcn_mfma_f32_16x16x16bf16_1k(A,B,C,0,0,0)
#endif

#if __has_builtin(__builtin_amdgcn_exp2f)
#define EXP2(x) __builtin_amdgcn_exp2f(x)
#else
#define EXP2(x) exp2f(x)
#endif

template<bool B> struct BoolC { static constexpr bool value = B; };

__device__ __forceinline__ void gload_lds16(const void* g, void* l) {
  __builtin_amdgcn_global_load_lds(
      (const __attribute__((address_space(1))) void*)g,
      (__attribute__((address_space(3))) void*)l,
      16, 0, 0);
}

// pack 2 floats -> 2 bf16 (round-half-up) in one v_perm
__device__ __forceinline__ unsigned pkbf(float a, float b) {
  unsigned ua = __builtin_bit_cast(unsigned, a) + 0x8000u;
  unsigned ub = __builtin_bit_cast(unsigned, b) + 0x8000u;
  return __builtin_amdgcn_perm(ub, ua, 0x07060302u);  // {a.hi16, b.hi16}
}

// raw barriers with compiler memory fences (NOT __syncthreads: that drains vmcnt(0))
#define BARRIER() do { asm volatile("" ::: "memory"); \
                       __builtin_amdgcn_s_barrier(); \
                       asm volatile("" ::: "memory"); } while (0)
#define BAR_VM(N) do { asm volatile("s_waitcnt vmcnt(" #N ")" ::: "memory"); \
                       __builtin_amdgcn_s_barrier(); \
                       asm volatile("" ::: "memory"); } while (0)

// ---------------------------------------------------------------------------
// One launch: cast x -> xb, {Wq*CSCALE,Wk,Wv} -> wqkv, Wp -> wpb,
// concat {bq*CSCALE,bk,bv} -> biasqkv (f32).
// ---------------------------------------------------------------------------
__global__ void fused_cast(const float* __restrict__ x, const float* __restrict__ Wq,
                           const float* __restrict__ Wk, const float* __restrict__ Wv,
                           const float* __restrict__ Wp, const float* __restrict__ bq,
                           const float* __restrict__ bk, const float* __restrict__ bv,
                           bf16* __restrict__ xb, bf16* __restrict__ wqkv,
                           bf16* __restrict__ wpb, float* __restrict__ biasqkv) {
  const int blk = blockIdx.x;
  const int i = threadIdx.x * 4;
  if (blk >= 12288) {
    const int wsel = blk - 12288;
    const float* bsrc = wsel == 0 ? bq : (wsel == 1 ? bk : bv);
    float4 bv4 = *(const float4*)(bsrc + i);
    if (wsel == 0) { bv4.x *= CSCALE; bv4.y *= CSCALE; bv4.z *= CSCALE; bv4.w *= CSCALE; }
    *(float4*)(biasqkv + wsel * 1024 + i) = bv4;
    return;
  }
  const float* src; bf16* dst; float sc = 1.0f;
  if (blk < 8192)       { src = x  + (size_t)blk * 1024;           dst = xb   + (size_t)blk * 1024; }
  else if (blk < 9216)  { src = Wq + (size_t)(blk - 8192) * 1024;  dst = wqkv + (size_t)(blk - 8192) * 1024; sc = CSCALE; }
  else if (blk < 10240) { src = Wk + (size_t)(blk - 9216) * 1024;  dst = wqkv + ((size_t)1 << 20) + (size_t)(blk - 9216) * 1024; }
  else if (blk < 11264) { src = Wv + (size_t)(blk - 10240) * 1024; dst = wqkv + ((size_t)2 << 20) + (size_t)(blk - 10240) * 1024; }
  else                  { src = Wp + (size_t)(blk - 11264) * 1024; dst = wpb  + (size_t)(blk - 11264) * 1024; }
  float4 v = *(const float4*)(src + i);
  union { short4v v; bf16 b[4]; } u;
  u.b[0] = __float2bfloat16(v.x * sc); u.b[1] = __float2bfloat16(v.y * sc);
  u.b[2] = __float2bfloat16(v.z * sc); u.b[3] = __float2bfloat16(v.w * sc);
  *(short4v*)(dst + i) = u.v;
}

// ---------------------------------------------------------------------------
// QKV GEMM, 8-phase 256x256 template (T2+T3+T4+T5).
// ---------------------------------------------------------------------------
#define PHASE_MFMA(MI0, NJ0) do { \
  __builtin_amdgcn_s_setprio(1); \
  _Pragma("unroll") \
  for (int m2 = 0; m2 < 4; ++m2) { \
    _Pragma("unroll") \
    for (int n2 = 0; n2 < 2; ++n2) { \
      acc[(MI0)+m2][(NJ0)+n2] = MFMA32(af[m2][0], bfr[(NJ0)+n2][0], acc[(MI0)+m2][(NJ0)+n2]); \
      acc[(MI0)+m2][(NJ0)+n2] = MFMA32(af[m2][1], bfr[(NJ0)+n2][1], acc[(MI0)+m2][(NJ0)+n2]); \
    } \
  } \
  __builtin_amdgcn_s_setprio(0); \
} while (0)

// Stage issue order per tile t (targets t+1): P1 B.j0, P2 A.j0, P3 B.j1, P4 A.j1.
// Next-tile P1 needs {B all, A.j0} -> all-but-last-2 -> BAR_VM(2) @ P4 end.
// This-tile P3 needs A.j1(t) -> all-but-last-4 -> BAR_VM(4) @ P2 end.
#define TILE(T, P) { \
  const int kn = ((T) + 1) * 64; \
  const bool st = (T) < 15; \
  const char* aB = rdA + (P) * 32768; \
  const char* bB = rdB + (P) * 32768; \
  char* sA = ldsA + ((P) ^ 1) * 32768 + wbase; \
  char* sB = ldsB + ((P) ^ 1) * 32768 + wbase; \
  /* ---- phase 1: A rows 0..63, B cols 0..31 of wave region ---- */ \
  _Pragma("unroll") \
  for (int m2 = 0; m2 < 4; ++m2) { \
    af[m2][0] = *(const short8*)(aB + m2 * 2048 + cs0); \
    af[m2][1] = *(const short8*)(aB + m2 * 2048 + cs1); \
  } \
  _Pragma("unroll") \
  for (int n2 = 0; n2 < 2; ++n2) { \
    bfr[n2][0] = *(const short8*)(bB + n2 * 2048 + cs0); \
    bfr[n2][1] = *(const short8*)(bB + n2 * 2048 + cs1); \
  } \
  if (st) { gload_lds16(gB + kn,          sB);         \
            gload_lds16(gB + 131072 + kn, sB + 16384); } \
  BARRIER(); \
  PHASE_MFMA(0, 0); \
  BARRIER(); \
  /* ---- phase 2: B cols 32..63 ---- */ \
  _Pragma("unroll") \
  for (int n2 = 2; n2 < 4; ++n2) { \
    bfr[n2][0] = *(const short8*)(bB + n2 * 2048 + cs0); \
    bfr[n2][1] = *(const short8*)(bB + n2 * 2048 + cs1); \
  } \
  if (st) { gload_lds16(gA + kn,          sA);         \
            gload_lds16(gA + 131072 + kn, sA + 16384); } \
  BARRIER(); \
  PHASE_MFMA(0, 2); \
  if (st) { BAR_VM(4); } else { BAR_VM(0); } \
  /* ---- phase 3: A rows 64..127 ---- */ \
  _Pragma("unroll") \
  for (int m2 = 0; m2 < 4; ++m2) { \
    af[m2][0] = *(const short8*)(aB + (4 + m2) * 2048 + cs0); \
    af[m2][1] = *(const short8*)(aB + (4 + m2) * 2048 + cs1); \
  } \
  if (st) { gload_lds16(gB + 65536 + kn,  sB + 8192);  \
            gload_lds16(gB + 196608 + kn, sB + 24576); } \
  BARRIER(); \
  PHASE_MFMA(4, 2); \
  BARRIER(); \
  /* ---- phase 4: register reuse only ---- */ \
  if (st) { gload_lds16(gA + 65536 + kn,  sA + 8192);  \
            gload_lds16(gA + 196608 + kn, sA + 24576); } \
  PHASE_MFMA(4, 0); \
  if (st) { BAR_VM(2); } \
}

__global__ __launch_bounds__(512, 2) void gemm_qkv8(
    const bf16* __restrict__ A, const bf16* __restrict__ B,
    const float* __restrict__ bias, bf16* __restrict__ qkout,
    bf16* __restrict__ vt) {
  __shared__ short smem[65536];   // 128 KiB: A [2p][2h][128r][64k] | B same @ +64KiB
  const int tid = threadIdx.x;
  const int l = tid & 63, w = tid >> 6;
  const int r = l & 15, qd = l >> 4;
  const int wm = w >> 2, wn = w & 3;

  // bijective XCD swizzle: 384 blocks, 48 per XCD (4 m-rows x 12 n-cols each)
  const int f0 = blockIdx.x;
  const int sid = (f0 & 7) * 48 + (f0 >> 3);
  const int m0 = (sid / 12) * 256;
  const int n0 = (sid % 12) * 256;

  const int rowA = tid >> 3;
  const int chk = (tid & 7) ^ (rowA & 7);
  const bf16* gA = A + (size_t)(m0 + rowA) * 1024 + chk * 8;
  const bf16* gB = B + (size_t)(n0 + rowA) * 1024 + chk * 8;
  char* ldsA = (char*)smem;
  char* ldsB = (char*)smem + 65536;
  const int wbase = w * 1024;     // wave-uniform LDS base; HW adds lane*16

  const char* rdA = (const char*)smem + wm * 16384 + r * 128;
  const char* rdB = (const char*)smem + 65536 + (wn >> 1) * 16384 +
                    ((wn & 1) * 64 + r) * 128;
  const int cs0 = (qd ^ (r & 7)) * 16;
  const int cs1 = ((4 + qd) ^ (r & 7)) * 16;

  f32x4 acc[8][4];
#pragma unroll
  for (int i = 0; i < 8; ++i)
#pragma unroll
    for (int j = 0; j < 4; ++j) acc[i][j] = (f32x4){0.f, 0.f, 0.f, 0.f};
  short8 af[4][2], bfr[4][2];

  { // prologue: stage tile 0 into parity 0 (order B.j0, A.j0, B.j1, A.j1)
    char* sA = ldsA + wbase;
    char* sB = ldsB + wbase;
    gload_lds16(gB,          sB);
    gload_lds16(gB + 131072, sB + 16384);
    gload_lds16(gA,          sA);
    gload_lds16(gA + 131072, sA + 16384);
    gload_lds16(gB + 65536,  sB + 8192);
    gload_lds16(gB + 196608, sB + 24576);
    gload_lds16(gA + 65536,  sA + 8192);
    gload_lds16(gA + 196608, sA + 24576);
    BAR_VM(2);                  // B(0) + A.j0(0) landed; A.j1(0) may fly
  }

#pragma unroll 1
  for (int tt = 0; tt < 8; ++tt) {
    TILE(tt * 2, 0)
    TILE(tt * 2 + 1, 1)
  }

  if (n0 < 2048) {
    // ---- qk epilogue: direct stores (16 lanes -> 32B contiguous pieces) ----
#pragma unroll
    for (int nt = 0; nt < 4; ++nt) {
      const int col = n0 + wn * 64 + nt * 16 + r;
      const float bv = bias[col];
#pragma unroll
      for (int mi = 0; mi < 8; ++mi) {
#pragma unroll
        for (int reg = 0; reg < 4; ++reg) {
          const int row = m0 + wm * 128 + mi * 16 + qd * 4 + reg;
          qkout[(size_t)row * QKLD + col] = __float2bfloat16(acc[mi][nt][reg] + bv);
        }
      }
    }
  } else {
    // ---- vt epilogue: LDS transpose to the exact vt memory image ----
    char* img = (char*)smem;
#pragma unroll
    for (int nt = 0; nt < 4; ++nt) {
      const int c_local = wn * 64 + nt * 16 + r;
      const float bv = bias[n0 + c_local];
      const int d7 = c_local & 7;
#pragma unroll
      for (int mi = 0; mi < 8; ++mi) {
        const int tbase = wm * 128 + mi * 16 + qd * 4;   // t_local of reg 0
        const int chunk = tbase >> 6;                    // 64-t chunk (128B)
        const int sbits = ((tbase >> 3) ^ d7) & 7;       // flash swizzle bits
        union { short4v v; bf16 b[4]; } u;
#pragma unroll
        for (int reg = 0; reg < 4; ++reg)
          u.b[reg] = __float2bfloat16(acc[mi][nt][reg] + bv);
        *(short4v*)(img + c_local * 512 + chunk * 128 + sbits * 16 + (qd & 1) * 8) = u.v;
      }
    }
    __syncthreads();   // ds_writes visible to all waves (vmcnt already drained)
    const int bb = m0 >> 11, tb = m0 & 2047;
    const int hb = (n0 - 2048) >> 6;
    const int off = (tid & 31) * 16;
#pragma unroll
    for (int i = 0; i < 16; ++i) {
      const int row = i * 16 + (tid >> 5);
      const int h2 = hb + (row >> 6), d = row & 63;
      const f32x4 vv = *(const f32x4*)(img + row * 512 + off);
      char* dst = (char*)(vt + ((size_t)(bb * 16 + h2) * 64 + d) * 2048 + tb) + off;
      *(f32x4*)dst = vv;
    }
  }
}

// ---------------------------------------------------------------------------
// Projection GEMM, 8-phase 256x128 tile. C[8192,1024] = A @ B^T + bias, f32.
// Same counted-vmcnt numerology as gemm_qkv8. Grid 256, 1 block/CU.
// ---------------------------------------------------------------------------
#define PJ_MFMA(MI0) do { \
  __builtin_amdgcn_s_setprio(1); \
  _Pragma("unroll") \
  for (int m2 = 0; m2 < 2; ++m2) { \
    _Pragma("unroll") \
    for (int nj = 0; nj < 2; ++nj) { \
      acc[(MI0)+m2][nj] = MFMA32(af[m2][0], bfr[nj][0], acc[(MI0)+m2][nj]); \
      acc[(MI0)+m2][nj] = MFMA32(af[m2][1], bfr[nj][1], acc[(MI0)+m2][nj]); \
    } \
  } \
  __builtin_amdgcn_s_setprio(0); \
} while (0)

#define PJ_TILE(T, P) { \
  const int kn = ((T) + 1) * 64; \
  const bool st = (T) < 15; \
  const char* aB = rdA + (P) * 32768; \
  const char* bB = rdB + (P) * 16384; \
  char* sA = ldsA + ((P) ^ 1) * 32768 + wbase; \
  char* sB = ldsB + ((P) ^ 1) * 16384 + wbase; \
  /* ---- P1: mi 0-1; all bfr ---- */ \
  _Pragma("unroll") \
  for (int m2 = 0; m2 < 2; ++m2) { \
    af[m2][0] = *(const short8*)(aB + m2 * 2048 + cs0); \
    af[m2][1] = *(const short8*)(aB + m2 * 2048 + cs1); \
  } \
  _Pragma("unroll") \
  for (int nj = 0; nj < 2; ++nj) { \
    bfr[nj][0] = *(const short8*)(bB + nj * 2048 + cs0); \
    bfr[nj][1] = *(const short8*)(bB + nj * 2048 + cs1); \
  } \
  if (st) { gload_lds16(gB + kn,         sB); \
            gload_lds16(gB + 65536 + kn, sB + 8192); } \
  BARRIER(); \
  PJ_MFMA(0); \
  BARRIER(); \
  /* ---- P2: mi 2-3 ---- */ \
  _Pragma("unroll") \
  for (int m2 = 0; m2 < 2; ++m2) { \
    af[m2][0] = *(const short8*)(aB + (2 + m2) * 2048 + cs0); \
    af[m2][1] = *(const short8*)(aB + (2 + m2) * 2048 + cs1); \
  } \
  if (st) { gload_lds16(gA + kn,          sA); \
            gload_lds16(gA + 131072 + kn, sA + 16384); } \
  BARRIER(); \
  PJ_MFMA(2); \
  if (st) { BAR_VM(4); } else { BAR_VM(0); } \
  /* ---- P3: mi 4-5 ---- */ \
  _Pragma("unroll") \
  for (int m2 = 0; m2 < 2; ++m2) { \
    af[m2][0] = *(const short8*)(aB + (4 + m2) * 2048 + cs0); \
    af[m2][1] = *(const short8*)(aB + (4 + m2) * 2048 + cs1); \
  } \
  if (st) { gload_lds16(gA + 65536 + kn,  sA + 8192); \
            gload_lds16(gA + 196608 + kn, sA + 24576); } \
  BARRIER(); \
  PJ_MFMA(4); \
  BARRIER(); \
  /* ---- P4: mi 6-7 ---- */ \
  _Pragma("unroll") \
  for (int m2 = 0; m2 < 2; ++m2) { \
    af[m2][0] = *(const short8*)(aB + (6 + m2) * 2048 + cs0); \
    af[m2][1] = *(const short8*)(aB + (6 + m2) * 2048 + cs1); \
  } \
  PJ_MFMA(6); \
  if (st) { BAR_VM(2); } \
}

__global__ __launch_bounds__(512, 2) void gemm_proj8(
    const bf16* __restrict__ A, const bf16* __restrict__ B,
    const float* __restrict__ bias, float* __restrict__ out) {
  __shared__ short smem[49152];   // 96 KiB: A [2p][256r][64k] | B [2p][128r][64k] @ +64KiB
  const int tid = threadIdx.x;
  const int l = tid & 63, w = tid >> 6;
  const int r = l & 15, qd = l >> 4;
  const int wm = w >> 2, wn = w & 3;

  // bijective XCD swizzle: 256 blocks = 32m x 8n, 32 per XCD
  const int f0 = blockIdx.x;
  const int sid = (f0 & 7) * 32 + (f0 >> 3);
  const int m0 = (sid >> 3) * 256;
  const int n0 = (sid & 7) * 128;

  const int rowA = tid >> 3;
  const int chk = (tid & 7) ^ (rowA & 7);
  const bf16* gA = A + (size_t)(m0 + rowA) * 1024 + chk * 8;
  const bf16* gB = B + (size_t)(n0 + rowA) * 1024 + chk * 8;
  char* ldsA = (char*)smem;
  char* ldsB = (char*)smem + 65536;
  const int wbase = w * 1024;

  const char* rdA = (const char*)smem + wm * 16384 + r * 128;
  const char* rdB = (const char*)smem + 65536 + (wn * 32 + r) * 128;
  const int cs0 = (qd ^ (r & 7)) * 16;
  const int cs1 = ((4 + qd) ^ (r & 7)) * 16;

  f32x4 acc[8][2];
#pragma unroll
  for (int i = 0; i < 8; ++i)
#pragma unroll
    for (int j = 0; j < 2; ++j) acc[i][j] = (f32x4){0.f, 0.f, 0.f, 0.f};
  short8 af[2][2], bfr[2][2];

  { // prologue: order B(2), A.j0(2), A.j1(2); B+A.j0 landed, A.j1 may fly
    char* sA = ldsA + wbase;
    char* sB = ldsB + wbase;
    gload_lds16(gB,          sB);
    gload_lds16(gB + 65536,  sB + 8192);
    gload_lds16(gA,          sA);
    gload_lds16(gA + 131072, sA + 16384);
    gload_lds16(gA + 65536,  sA + 8192);
    gload_lds16(gA + 196608, sA + 24576);
    BAR_VM(2);
  }

#pragma unroll 1
  for (int tt = 0; tt < 8; ++tt) {
    PJ_TILE(tt * 2, 0)
    PJ_TILE(tt * 2 + 1, 1)
  }

  // epilogue: f32 direct stores
#pragma unroll
  for (int nj = 0; nj < 2; ++nj) {
    const int col = n0 + wn * 32 + nj * 16 + r;
    const float bv = bias[col];
#pragma unroll
    for (int mi = 0; mi < 8; ++mi) {
#pragma unroll
      for (int reg = 0; reg < 4; ++reg) {
        const int row = m0 + wm * 128 + mi * 16 + qd * 4 + reg;
        out[(size_t)row * 1024 + col] = acc[mi][nj][reg] + bv;
      }
    }
  }
}

// ---------------------------------------------------------------------------
// Causal flash attention v9b (round 11, verified best): kt-parity split
// across 2 wave-groups, all-LDS-ring staging (V+K, 4-deep, post-barrier
// issue), launch_bounds(512,2) — 112 VGPR, no spill. 78.2us measured.
// ---------------------------------------------------------------------------
__global__ __launch_bounds__(512, 2) void flash9(
    const bf16* __restrict__ qk, const bf16* __restrict__ vt,
    const float* __restrict__ x, bf16* __restrict__ pb) {
  const int bh = blockIdx.x;            // 0..63 -> XCD = bh%8
  const int ip = blockIdx.y;            // 0..7
  const int b = bh >> 4, h = bh & 15;
  const int qt[4] = { 31 - ip, 23 - ip, ip + 8, ip };   // descending
  const int tid = threadIdx.x, l = tid & 63, w = tid >> 6;
  const int wg = w & 3, grp = w >> 2;   // wg: q-row group; grp: kt parity
  const int r = l & 15, quad = l >> 4;

  __shared__ __align__(16) char smem[65536];  // V ring [4][8K] | K ring [4][8K] @32K

  const bf16* Qbase = qk + (size_t)b * TSEQ * QKLD + h * HD;
  const bf16* Kbase = Qbase + 1024;
  const bf16* Vhead = vt + (size_t)bh * 64 * 2048;

  // V staging: slot tid -> d=tid>>3, chunk tid&7 (vt image rows verbatim)
  const bf16* vg = Vhead + (size_t)(tid >> 3) * 2048 + (tid & 7) * 8;
  // K staging: dest row=tid>>3, phys chunk tid&7 holds global chunk ^(row&7)
  const int krow = tid >> 3;
  const bf16* kg = Kbase + (size_t)krow * QKLD + ((tid & 7) ^ (krow & 7)) * 8;
  char* vbase = smem + w * 1024;              // + (kt&3)*8192
  char* kbase = smem + 32768 + w * 1024;      // + (kt&3)*8192

  // Q fragments (B-operand of S^T: n=lane&15=qrow, k=quad*8+j)
  short8 qf0[4], qf1[4];
#pragma unroll
  for (int t = 0; t < 4; ++t) {
    const bf16* qp = Qbase + (size_t)(qt[t] * 64 + wg * 16 + r) * QKLD + quad * 8;
    qf0[t] = *(const short8*)qp;
    qf1[t] = *(const short8*)(qp + 32);
  }

  f32x4 o[4][4], lac[4];
#pragma unroll
  for (int t = 0; t < 4; ++t) {
    lac[t] = (f32x4){0.f, 0.f, 0.f, 0.f};
#pragma unroll
    for (int nt = 0; nt < 4; ++nt) o[t][nt] = (f32x4){0.f, 0.f, 0.f, 0.f};
  }

  short4v ones4;
#pragma unroll
  for (int j = 0; j < 4; ++j) ones4[j] = (short)0x3F80;  // bf16 1.0

  short4v vf[4][4];

  const int ktmax = qt[0];
  const int qrow_l = wg * 16 + r;

  // prologue: stage V(0),V(1),K(0),K(1) into ring slots 0,1
  gload_lds16(vg,           vbase);
  gload_lds16(vg + 64,      vbase + 8192);
  gload_lds16(kg,           kbase);
  gload_lds16(kg + 131072,  kbase + 8192);    // kt stride = 64*QKLD elems

  auto tilestep = [&](int t, auto diagc, short8 (&k0)[4], short8 (&k1)[4]) {
    constexpr bool D = decltype(diagc)::value;
    f32x4 s[4];
    __builtin_amdgcn_s_setprio(1);
#pragma unroll
    for (int g = 0; g < 4; ++g) {
      f32x4 a = (f32x4){0.f, 0.f, 0.f, 0.f};
      a = MFMA32(k0[g], qf0[t], a);     // A=K, B=Q -> S^T[key][q]
      a = MFMA32(k1[g], qf1[t], a);
      s[g] = a;
    }
    __builtin_amdgcn_s_setprio(0);
    short4v pA[4];
#pragma unroll
    for (int g = 0; g < 4; ++g) {
      float p[4];
#pragma unroll
      for (int reg = 0; reg < 4; ++reg) {
        float e = EXP2(s[g][reg]);      // scale pre-folded into Q
        if (D) {
          const int kj = g * 16 + quad * 4 + reg;   // key local (kt==qt)
          if (kj > qrow_l) e = 0.f;
        }
        p[reg] = e;
      }
      union { short4v v; unsigned u[2]; } pu;
      pu.u[0] = pkbf(p[0], p[1]);
      pu.u[1] = pkbf(p[2], p[3]);
      pA[g] = pu.v;
    }
    __builtin_amdgcn_s_setprio(1);
#pragma unroll
    for (int nt = 0; nt < 4; ++nt)
#pragma unroll
      for (int g = 0; g < 4; ++g)
        o[t][nt] = MFMA16(pA[g], vf[nt][g], o[t][nt]);
#pragma unroll
    for (int g = 0; g < 4; ++g)
      lac[t] = MFMA16(pA[g], ones4, lac[t]);
    __builtin_amdgcn_s_setprio(0);
  };

  const int niter = (ktmax >> 1) + 1;
#pragma unroll 1
  for (int i = 0; i < niter; ++i) {
    const int kt = 2 * i + grp;
    const bool act = kt <= ktmax;       // group-uniform (whole waves)
    __syncthreads();                    // prev-iteration stages landed (covered)
    // prefetch next pair (tiles 2i+2, 2i+3) into slots freed at iter i-1
    const int nx0 = 2 * i + 2, nx1 = 2 * i + 3;
    if (nx0 <= ktmax) {
      gload_lds16(vg + nx0 * 64,            smem + (nx0 & 3) * 8192 + w * 1024);
      gload_lds16(kg + (size_t)nx0 * 131072, smem + 32768 + (nx0 & 3) * 8192 + w * 1024);
    }
    if (nx1 <= ktmax) {
      gload_lds16(vg + nx1 * 64,            smem + (nx1 & 3) * 8192 + w * 1024);
      gload_lds16(kg + (size_t)nx1 * 131072, smem + 32768 + (nx1 & 3) * 8192 + w * 1024);
    }
    if (act) {
      // K frags from LDS ring (XOR-swizzle read; row&7 == r&7 since g*16%8==0)
      short8 k0[4], k1[4];
      {
        const bf16* Kt = (const bf16*)(smem + 32768 + (kt & 3) * 8192);
#pragma unroll
        for (int g = 0; g < 4; ++g) {
          const bf16* kp = Kt + (g * 16 + r) * 64;
          k0[g] = *(const short8*)(kp + ((quad ^ (r & 7)) * 8));
          k1[g] = *(const short8*)(kp + (((quad + 4) ^ (r & 7)) * 8));
        }
      }
      {
        const bf16* V = (const bf16*)smem + (kt & 3) * 4096;
#pragma unroll
        for (int nt = 0; nt < 4; ++nt)
#pragma unroll
          for (int g = 0; g < 4; ++g)
            vf[nt][g] = *(const short4v*)(V + (nt * 16 + r) * 64 +
                                          (((g * 2 + (quad >> 1)) ^ (r & 7)) * 8) + (quad & 1) * 4);
      }
      if (kt == qt[0]) tilestep(0, BoolC<true>{}, k0, k1);
      else             tilestep(0, BoolC<false>{}, k0, k1);
      if (kt <= qt[1]) { if (kt == qt[1]) tilestep(1, BoolC<true>{}, k0, k1);
                         else             tilestep(1, BoolC<false>{}, k0, k1); }
      if (kt <= qt[2]) { if (kt == qt[2]) tilestep(2, BoolC<true>{}, k0, k1);
                         else             tilestep(2, BoolC<false>{}, k0, k1); }
      if (kt <= qt[3]) { if (kt == qt[3]) tilestep(3, BoolC<true>{}, k0, k1);
                         else             tilestep(3, BoolC<false>{}, k0, k1); }
    }
  }

  // ---- combine (2 rounds) + split epilogue (reuses smem[0..40K)) ----
  float* combO = (float*)smem;                 // 32 KB: [wg*64+l][8 chunks x 16B]
  float* combL = (float*)(smem + 32768);       // 8 KB : [wg*64+l][2 tiles x 16B]
  const int lb128 = (wg * 64 + l) * 32;        // float index of lane's 128B block
  const int lbl = (wg * 64 + l) * 8;

  __syncthreads();                             // all ring reads + stages complete
#pragma unroll
  for (int rnd = 0; rnd < 2; ++rnd) {
    const int wgrp = (rnd == 0) ? 1 : 0;       // writer group this round
    if (grp == wgrp) {
#pragma unroll
      for (int t2 = 0; t2 < 2; ++t2) {
        const int tt = rnd * 2 + t2;
#pragma unroll
        for (int nt = 0; nt < 4; ++nt)
          *(f32x4*)&combO[lb128 + (((t2 * 4 + nt) ^ (l & 7)) << 2)] = o[tt][nt];
        *(f32x4*)&combL[lbl + t2 * 4] = lac[tt];
      }
    }
    __syncthreads();
    if (grp != wgrp) {
#pragma unroll
      for (int t2 = 0; t2 < 2; ++t2) {
        const int tt = rnd * 2 + t2;
        const f32x4 ls = *(const f32x4*)&combL[lbl + t2 * 4];
#pragma unroll
        for (int j2 = 0; j2 < 4; ++j2) lac[tt][j2] += ls[j2];
#pragma unroll
        for (int nt = 0; nt < 4; ++nt) {
          const f32x4 ov = *(const f32x4*)&combO[lb128 + (((t2 * 4 + nt) ^ (l & 7)) << 2)];
#pragma unroll
          for (int j2 = 0; j2 < 4; ++j2) o[tt][nt][j2] += ov[j2];
        }
        // epilogue for tile tt: O /= l, +residual, bf16 store
#pragma unroll
        for (int reg = 0; reg < 4; ++reg) {
          const float inv = 1.0f / lac[tt][reg];
          const int row = qt[tt] * 64 + wg * 16 + quad * 4 + reg;
          const float* xr = x + (size_t)(b * TSEQ + row) * EMB + h * HD;
          bf16* pr = pb + (size_t)(b * TSEQ + row) * EMB + h * HD;
#pragma unroll
          for (int nt = 0; nt < 4; ++nt) {
            const int d = nt * 16 + r;
            pr[d] = __float2bfloat16(o[tt][nt][reg] * inv + xr[d]);
          }
        }
      }
    }
    if (rnd == 0) __syncthreads();             // round-1 reads done before round-2 writes
  }
}

// ---------------------------------------------------------------------------
// In-place LayerNorm over last dim (1024). One block per row, 256 thr x 4.
// ---------------------------------------------------------------------------
__global__ __launch_bounds__(256) void ln_kernel(float* __restrict__ out,
                                                 const float* __restrict__ gamma,
                                                 const float* __restrict__ beta) {
  const int row = blockIdx.x;
  const int tid = threadIdx.x;
  float* p = out + (size_t)row * EMB;
  float4 v = ((const float4*)p)[tid];
  float s = v.x + v.y + v.z + v.w;
  float ss = v.x * v.x + v.y * v.y + v.z * v.z + v.w * v.w;
#pragma unroll
  for (int m = 1; m < 64; m <<= 1) {
    s += __shfl_xor(s, m, 64);
    ss += __shfl_xor(ss, m, 64);
  }
  __shared__ float red[8];
  const int w = tid >> 6, l = tid & 63;
  if (l == 0) { red[w] = s; red[4 + w] = ss; }
  __syncthreads();
  s = red[0] + red[1] + red[2] + red[3];
  ss = red[4] + red[5] + red[6] + red[7];
  const float mu = s * (1.0f / EMB);
  const float var = ss * (1.0f / EMB) - mu * mu;
  const float rs = rsqrtf(var + 1e-6f);
  const float4 g = ((const float4*)gamma)[tid];
  const float4 bb = ((const float4*)beta)[tid];
  float4 o;
  o.x = (v.x - mu) * rs * g.x + bb.x;
  o.y = (v.y - mu) * rs * g.y + bb.y;
  o.z = (v.z - mu) * rs * g.z + bb.z;
  o.w = (v.w - mu) * rs * g.w + bb.w;
  ((float4*)p)[tid] = o;
}

// ---------------------------------------------------------------------------
extern "C" void kernel_launch(void* const* d_in, const int* in_sizes, int n_in,
                              void* d_out, int out_size, void* d_ws, size_t ws_size,
                              hipStream_t stream) {
  const float* x     = (const float*)d_in[0];
  const float* Wq    = (const float*)d_in[1];
  const float* bq    = (const float*)d_in[2];
  const float* Wk    = (const float*)d_in[3];
  const float* bk    = (const float*)d_in[4];
  const float* Wv    = (const float*)d_in[5];
  const float* bv    = (const float*)d_in[6];
  const float* Wp    = (const float*)d_in[7];
  const float* bp    = (const float*)d_in[8];
  const float* gamma = (const float*)d_in[9];
  const float* beta  = (const float*)d_in[10];
  float* out = (float*)d_out;

  // ws: xb 0-16M (reused as pb), wqkv 16-22M, wpb 22-24M, bqkv 24M(+12KB),
  // qk 25-57M (stride 2048), vt 57-73M ([b][h][d][T] swizzled)
  if (ws_size < (size_t)74 * 1024 * 1024) {
    printf("kernel_launch: ws_size %zu too small\n", ws_size);
    return;
  }
  char* ws = (char*)d_ws;
  bf16* xb    = (bf16*)ws;
  bf16* wqkv  = (bf16*)(ws + ((size_t)16 << 20));
  bf16* wpb   = (bf16*)(ws + ((size_t)22 << 20));
  float* bqkv = (float*)(ws + ((size_t)24 << 20));
  bf16* qkbuf = (bf16*)(ws + ((size_t)25 << 20));
  bf16* vtbuf = (bf16*)(ws + ((size_t)57 << 20));
  bf16* pbuf  = xb;  // xb dead after QKV GEMM

  fused_cast<<<12291, 256, 0, stream>>>(x, Wq, Wk, Wv, Wp, bq, bk, bv, xb, wqkv, wpb, bqkv);

  gemm_qkv8<<<dim3(384), dim3(512), 0, stream>>>(xb, wqkv, bqkv, qkbuf, vtbuf);

  flash9<<<dim3(64, 8), 512, 0, stream>>>(qkbuf, vtbuf, x, pbuf);

  gemm_proj8<<<dim3(256), dim3(512), 0, stream>>>(pbuf, wpb, bp, out);

  ln_kernel<<<BT, 256, 0, stream>>>(out, gamma, beta);
}

// Round 15
// 269.662 us; speedup vs baseline: 1.0281x; 1.0248x over previous
//
#include <hip/hip_runtime.h>
#include <hip/hip_bf16.h>
#include <cstdint>
#include <cstdio>

#define EMB    1024
#define HEADS  16
#define HD     64
#define TSEQ   2048
#define NBATCH 4
#define BT     (NBATCH*TSEQ)   // 8192
#define QKVN   3072            // fused QKV GEMM output width
#define QKLD   2048            // Q,K buffer row stride

// log2(e) / sqrt(2048) — folded into Wq/bq at cast time
#define CSCALE (1.4426950408889634f * 0.022097086912079608f)

typedef __hip_bfloat16 bf16;
typedef __attribute__((ext_vector_type(8))) short short8;   // 8 bf16 (K=32 MFMA A/B frag)
typedef __attribute__((ext_vector_type(4))) short short4v;  // 4 bf16 (K=16 MFMA A/B frag)
typedef __attribute__((ext_vector_type(4))) float f32x4;    // MFMA C/D frag

#define MFMA32(A,B,C) __builtin_amdgcn_mfma_f32_16x16x32_bf16(A,B,C,0,0,0)
#if __has_builtin(__builtin_amdgcn_mfma_f32_16x16x16_bf16)
#define MFMA16(A,B,C) __builtin_amdgcn_mfma_f32_16x16x16_bf16(A,B,C,0,0,0)
#else
#define MFMA16(A,B,C) __builtin_amdgcn_mfma_f32_16x16x16bf16_1k(A,B,C,0,0,0)
#endif

#if __has_builtin(__builtin_amdgcn_exp2f)
#define EXP2(x) __builtin_amdgcn_exp2f(x)
#else
#define EXP2(x) exp2f(x)
#endif

template<bool B> struct BoolC { static constexpr bool value = B; };

__device__ __forceinline__ void gload_lds16(const void* g, void* l) {
  __builtin_amdgcn_global_load_lds(
      (const __attribute__((address_space(1))) void*)g,
      (__attribute__((address_space(3))) void*)l,
      16, 0, 0);
}

// pack 2 floats -> 2 bf16 (round-half-up) in one v_perm
__device__ __forceinline__ unsigned pkbf(float a, float b) {
  unsigned ua = __builtin_bit_cast(unsigned, a) + 0x8000u;
  unsigned ub = __builtin_bit_cast(unsigned, b) + 0x8000u;
  return __builtin_amdgcn_perm(ub, ua, 0x07060302u);  // {a.hi16, b.hi16}
}

// raw barriers with compiler memory fences (NOT __syncthreads: that drains vmcnt(0))
#define BARRIER() do { asm volatile("" ::: "memory"); \
                       __builtin_amdgcn_s_barrier(); \
                       asm volatile("" ::: "memory"); } while (0)
#define BAR_VM(N) do { asm volatile("s_waitcnt vmcnt(" #N ")" ::: "memory"); \
                       __builtin_amdgcn_s_barrier(); \
                       asm volatile("" ::: "memory"); } while (0)

// ---------------------------------------------------------------------------
// One launch: cast x -> xb, {Wq*CSCALE,Wk,Wv} -> wqkv, Wp -> wpb,
// concat {bq*CSCALE,bk,bv} -> biasqkv (f32).
// ---------------------------------------------------------------------------
__global__ void fused_cast(const float* __restrict__ x, const float* __restrict__ Wq,
                           const float* __restrict__ Wk, const float* __restrict__ Wv,
                           const float* __restrict__ Wp, const float* __restrict__ bq,
                           const float* __restrict__ bk, const float* __restrict__ bv,
                           bf16* __restrict__ xb, bf16* __restrict__ wqkv,
                           bf16* __restrict__ wpb, float* __restrict__ biasqkv) {
  const int blk = blockIdx.x;
  const int i = threadIdx.x * 4;
  if (blk >= 12288) {
    const int wsel = blk - 12288;
    const float* bsrc = wsel == 0 ? bq : (wsel == 1 ? bk : bv);
    float4 bv4 = *(const float4*)(bsrc + i);
    if (wsel == 0) { bv4.x *= CSCALE; bv4.y *= CSCALE; bv4.z *= CSCALE; bv4.w *= CSCALE; }
    *(float4*)(biasqkv + wsel * 1024 + i) = bv4;
    return;
  }
  const float* src; bf16* dst; float sc = 1.0f;
  if (blk < 8192)       { src = x  + (size_t)blk * 1024;           dst = xb   + (size_t)blk * 1024; }
  else if (blk < 9216)  { src = Wq + (size_t)(blk - 8192) * 1024;  dst = wqkv + (size_t)(blk - 8192) * 1024; sc = CSCALE; }
  else if (blk < 10240) { src = Wk + (size_t)(blk - 9216) * 1024;  dst = wqkv + ((size_t)1 << 20) + (size_t)(blk - 9216) * 1024; }
  else if (blk < 11264) { src = Wv + (size_t)(blk - 10240) * 1024; dst = wqkv + ((size_t)2 << 20) + (size_t)(blk - 10240) * 1024; }
  else                  { src = Wp + (size_t)(blk - 11264) * 1024; dst = wpb  + (size_t)(blk - 11264) * 1024; }
  float4 v = *(const float4*)(src + i);
  union { short4v v; bf16 b[4]; } u;
  u.b[0] = __float2bfloat16(v.x * sc); u.b[1] = __float2bfloat16(v.y * sc);
  u.b[2] = __float2bfloat16(v.z * sc); u.b[3] = __float2bfloat16(v.w * sc);
  *(short4v*)(dst + i) = u.v;
}

// ---------------------------------------------------------------------------
// QKV GEMM, 8-phase 256x256 template (T2+T3+T4+T5).
// ---------------------------------------------------------------------------
#define PHASE_MFMA(MI0, NJ0) do { \
  __builtin_amdgcn_s_setprio(1); \
  _Pragma("unroll") \
  for (int m2 = 0; m2 < 4; ++m2) { \
    _Pragma("unroll") \
    for (int n2 = 0; n2 < 2; ++n2) { \
      acc[(MI0)+m2][(NJ0)+n2] = MFMA32(af[m2][0], bfr[(NJ0)+n2][0], acc[(MI0)+m2][(NJ0)+n2]); \
      acc[(MI0)+m2][(NJ0)+n2] = MFMA32(af[m2][1], bfr[(NJ0)+n2][1], acc[(MI0)+m2][(NJ0)+n2]); \
    } \
  } \
  __builtin_amdgcn_s_setprio(0); \
} while (0)

// Stage issue order per tile t (targets t+1): P1 B.j0, P2 A.j0, P3 B.j1, P4 A.j1.
// Next-tile P1 needs {B all, A.j0} -> all-but-last-2 -> BAR_VM(2) @ P4 end.
// This-tile P3 needs A.j1(t) -> all-but-last-4 -> BAR_VM(4) @ P2 end.
#define TILE(T, P) { \
  const int kn = ((T) + 1) * 64; \
  const bool st = (T) < 15; \
  const char* aB = rdA + (P) * 32768; \
  const char* bB = rdB + (P) * 32768; \
  char* sA = ldsA + ((P) ^ 1) * 32768 + wbase; \
  char* sB = ldsB + ((P) ^ 1) * 32768 + wbase; \
  /* ---- phase 1: A rows 0..63, B cols 0..31 of wave region ---- */ \
  _Pragma("unroll") \
  for (int m2 = 0; m2 < 4; ++m2) { \
    af[m2][0] = *(const short8*)(aB + m2 * 2048 + cs0); \
    af[m2][1] = *(const short8*)(aB + m2 * 2048 + cs1); \
  } \
  _Pragma("unroll") \
  for (int n2 = 0; n2 < 2; ++n2) { \
    bfr[n2][0] = *(const short8*)(bB + n2 * 2048 + cs0); \
    bfr[n2][1] = *(const short8*)(bB + n2 * 2048 + cs1); \
  } \
  if (st) { gload_lds16(gB + kn,          sB);         \
            gload_lds16(gB + 131072 + kn, sB + 16384); } \
  BARRIER(); \
  PHASE_MFMA(0, 0); \
  BARRIER(); \
  /* ---- phase 2: B cols 32..63 ---- */ \
  _Pragma("unroll") \
  for (int n2 = 2; n2 < 4; ++n2) { \
    bfr[n2][0] = *(const short8*)(bB + n2 * 2048 + cs0); \
    bfr[n2][1] = *(const short8*)(bB + n2 * 2048 + cs1); \
  } \
  if (st) { gload_lds16(gA + kn,          sA);         \
            gload_lds16(gA + 131072 + kn, sA + 16384); } \
  BARRIER(); \
  PHASE_MFMA(0, 2); \
  if (st) { BAR_VM(4); } else { BAR_VM(0); } \
  /* ---- phase 3: A rows 64..127 ---- */ \
  _Pragma("unroll") \
  for (int m2 = 0; m2 < 4; ++m2) { \
    af[m2][0] = *(const short8*)(aB + (4 + m2) * 2048 + cs0); \
    af[m2][1] = *(const short8*)(aB + (4 + m2) * 2048 + cs1); \
  } \
  if (st) { gload_lds16(gB + 65536 + kn,  sB + 8192);  \
            gload_lds16(gB + 196608 + kn, sB + 24576); } \
  BARRIER(); \
  PHASE_MFMA(4, 2); \
  BARRIER(); \
  /* ---- phase 4: register reuse only ---- */ \
  if (st) { gload_lds16(gA + 65536 + kn,  sA + 8192);  \
            gload_lds16(gA + 196608 + kn, sA + 24576); } \
  PHASE_MFMA(4, 0); \
  if (st) { BAR_VM(2); } \
}

__global__ __launch_bounds__(512, 2) void gemm_qkv8(
    const bf16* __restrict__ A, const bf16* __restrict__ B,
    const float* __restrict__ bias, bf16* __restrict__ qkout,
    bf16* __restrict__ vt) {
  __shared__ short smem[65536];   // 128 KiB: A [2p][2h][128r][64k] | B same @ +64KiB
  const int tid = threadIdx.x;
  const int l = tid & 63, w = tid >> 6;
  const int r = l & 15, qd = l >> 4;
  const int wm = w >> 2, wn = w & 3;

  // Long-blocks-first schedule: f0<128 -> the 128 vt blocks (longer epilogue)
  // dispatched first so the 128 second-round blocks (qk, shorter) pair with
  // qk CUs: wall = max(2*T_qk, T_vt) instead of T_qk+T_vt. XCD = f0&7,
  // bijective within each class.
  const int f0 = blockIdx.x;
  int m0, n0;
  if (f0 < 128) {
    const int v = (f0 & 7) * 16 + (f0 >> 3);   // 0..127
    m0 = (v >> 2) * 256;
    n0 = 2048 + (v & 3) * 256;
  } else {
    const int q = f0 - 128;                    // 0..255
    const int u = (q & 7) * 32 + (q >> 3);     // 0..255
    m0 = (u >> 3) * 256;
    n0 = (u & 7) * 256;
  }

  const int rowA = tid >> 3;
  const int chk = (tid & 7) ^ (rowA & 7);
  const bf16* gA = A + (size_t)(m0 + rowA) * 1024 + chk * 8;
  const bf16* gB = B + (size_t)(n0 + rowA) * 1024 + chk * 8;
  char* ldsA = (char*)smem;
  char* ldsB = (char*)smem + 65536;
  const int wbase = w * 1024;     // wave-uniform LDS base; HW adds lane*16

  const char* rdA = (const char*)smem + wm * 16384 + r * 128;
  const char* rdB = (const char*)smem + 65536 + (wn >> 1) * 16384 +
                    ((wn & 1) * 64 + r) * 128;
  const int cs0 = (qd ^ (r & 7)) * 16;
  const int cs1 = ((4 + qd) ^ (r & 7)) * 16;

  f32x4 acc[8][4];
#pragma unroll
  for (int i = 0; i < 8; ++i)
#pragma unroll
    for (int j = 0; j < 4; ++j) acc[i][j] = (f32x4){0.f, 0.f, 0.f, 0.f};
  short8 af[4][2], bfr[4][2];

  { // prologue: stage tile 0 into parity 0 (order B.j0, A.j0, B.j1, A.j1)
    char* sA = ldsA + wbase;
    char* sB = ldsB + wbase;
    gload_lds16(gB,          sB);
    gload_lds16(gB + 131072, sB + 16384);
    gload_lds16(gA,          sA);
    gload_lds16(gA + 131072, sA + 16384);
    gload_lds16(gB + 65536,  sB + 8192);
    gload_lds16(gB + 196608, sB + 24576);
    gload_lds16(gA + 65536,  sA + 8192);
    gload_lds16(gA + 196608, sA + 24576);
    BAR_VM(2);                  // B(0) + A.j0(0) landed; A.j1(0) may fly
  }

#pragma unroll 1
  for (int tt = 0; tt < 8; ++tt) {
    TILE(tt * 2, 0)
    TILE(tt * 2 + 1, 1)
  }

  if (n0 < 2048) {
    // ---- qk epilogue: direct stores (16 lanes -> 32B contiguous pieces) ----
#pragma unroll
    for (int nt = 0; nt < 4; ++nt) {
      const int col = n0 + wn * 64 + nt * 16 + r;
      const float bv = bias[col];
#pragma unroll
      for (int mi = 0; mi < 8; ++mi) {
#pragma unroll
        for (int reg = 0; reg < 4; ++reg) {
          const int row = m0 + wm * 128 + mi * 16 + qd * 4 + reg;
          qkout[(size_t)row * QKLD + col] = __float2bfloat16(acc[mi][nt][reg] + bv);
        }
      }
    }
  } else {
    // ---- vt epilogue: LDS transpose to the exact vt memory image ----
    char* img = (char*)smem;
#pragma unroll
    for (int nt = 0; nt < 4; ++nt) {
      const int c_local = wn * 64 + nt * 16 + r;
      const float bv = bias[n0 + c_local];
      const int d7 = c_local & 7;
#pragma unroll
      for (int mi = 0; mi < 8; ++mi) {
        const int tbase = wm * 128 + mi * 16 + qd * 4;   // t_local of reg 0
        const int chunk = tbase >> 6;                    // 64-t chunk (128B)
        const int sbits = ((tbase >> 3) ^ d7) & 7;       // flash swizzle bits
        union { short4v v; bf16 b[4]; } u;
#pragma unroll
        for (int reg = 0; reg < 4; ++reg)
          u.b[reg] = __float2bfloat16(acc[mi][nt][reg] + bv);
        *(short4v*)(img + c_local * 512 + chunk * 128 + sbits * 16 + (qd & 1) * 8) = u.v;
      }
    }
    __syncthreads();   // ds_writes visible to all waves (vmcnt already drained)
    const int bb = m0 >> 11, tb = m0 & 2047;
    const int hb = (n0 - 2048) >> 6;
    const int off = (tid & 31) * 16;
#pragma unroll
    for (int i = 0; i < 16; ++i) {
      const int row = i * 16 + (tid >> 5);
      const int h2 = hb + (row >> 6), d = row & 63;
      const f32x4 vv = *(const f32x4*)(img + row * 512 + off);
      char* dst = (char*)(vt + ((size_t)(bb * 16 + h2) * 64 + d) * 2048 + tb) + off;
      *(f32x4*)dst = vv;
    }
  }
}

// ---------------------------------------------------------------------------
// Projection GEMM, 8-phase 256x128 tile. C[8192,1024] = A @ B^T + bias, f32.
// Same counted-vmcnt numerology as gemm_qkv8. Grid 256, 1 block/CU.
// ---------------------------------------------------------------------------
#define PJ_MFMA(MI0) do { \
  __builtin_amdgcn_s_setprio(1); \
  _Pragma("unroll") \
  for (int m2 = 0; m2 < 2; ++m2) { \
    _Pragma("unroll") \
    for (int nj = 0; nj < 2; ++nj) { \
      acc[(MI0)+m2][nj] = MFMA32(af[m2][0], bfr[nj][0], acc[(MI0)+m2][nj]); \
      acc[(MI0)+m2][nj] = MFMA32(af[m2][1], bfr[nj][1], acc[(MI0)+m2][nj]); \
    } \
  } \
  __builtin_amdgcn_s_setprio(0); \
} while (0)

#define PJ_TILE(T, P) { \
  const int kn = ((T) + 1) * 64; \
  const bool st = (T) < 15; \
  const char* aB = rdA + (P) * 32768; \
  const char* bB = rdB + (P) * 16384; \
  char* sA = ldsA + ((P) ^ 1) * 32768 + wbase; \
  char* sB = ldsB + ((P) ^ 1) * 16384 + wbase; \
  /* ---- P1: mi 0-1; all bfr ---- */ \
  _Pragma("unroll") \
  for (int m2 = 0; m2 < 2; ++m2) { \
    af[m2][0] = *(const short8*)(aB + m2 * 2048 + cs0); \
    af[m2][1] = *(const short8*)(aB + m2 * 2048 + cs1); \
  } \
  _Pragma("unroll") \
  for (int nj = 0; nj < 2; ++nj) { \
    bfr[nj][0] = *(const short8*)(bB + nj * 2048 + cs0); \
    bfr[nj][1] = *(const short8*)(bB + nj * 2048 + cs1); \
  } \
  if (st) { gload_lds16(gB + kn,         sB); \
            gload_lds16(gB + 65536 + kn, sB + 8192); } \
  BARRIER(); \
  PJ_MFMA(0); \
  BARRIER(); \
  /* ---- P2: mi 2-3 ---- */ \
  _Pragma("unroll") \
  for (int m2 = 0; m2 < 2; ++m2) { \
    af[m2][0] = *(const short8*)(aB + (2 + m2) * 2048 + cs0); \
    af[m2][1] = *(const short8*)(aB + (2 + m2) * 2048 + cs1); \
  } \
  if (st) { gload_lds16(gA + kn,          sA); \
            gload_lds16(gA + 131072 + kn, sA + 16384); } \
  BARRIER(); \
  PJ_MFMA(2); \
  if (st) { BAR_VM(4); } else { BAR_VM(0); } \
  /* ---- P3: mi 4-5 ---- */ \
  _Pragma("unroll") \
  for (int m2 = 0; m2 < 2; ++m2) { \
    af[m2][0] = *(const short8*)(aB + (4 + m2) * 2048 + cs0); \
    af[m2][1] = *(const short8*)(aB + (4 + m2) * 2048 + cs1); \
  } \
  if (st) { gload_lds16(gA + 65536 + kn,  sA + 8192); \
            gload_lds16(gA + 196608 + kn, sA + 24576); } \
  BARRIER(); \
  PJ_MFMA(4); \
  BARRIER(); \
  /* ---- P4: mi 6-7 ---- */ \
  _Pragma("unroll") \
  for (int m2 = 0; m2 < 2; ++m2) { \
    af[m2][0] = *(const short8*)(aB + (6 + m2) * 2048 + cs0); \
    af[m2][1] = *(const short8*)(aB + (6 + m2) * 2048 + cs1); \
  } \
  PJ_MFMA(6); \
  if (st) { BAR_VM(2); } \
}

__global__ __launch_bounds__(512, 2) void gemm_proj8(
    const bf16* __restrict__ A, const bf16* __restrict__ B,
    const float* __restrict__ bias, float* __restrict__ out) {
  __shared__ short smem[49152];   // 96 KiB: A [2p][256r][64k] | B [2p][128r][64k] @ +64KiB
  const int tid = threadIdx.x;
  const int l = tid & 63, w = tid >> 6;
  const int r = l & 15, qd = l >> 4;
  const int wm = w >> 2, wn = w & 3;

  // bijective XCD swizzle: 256 blocks = 32m x 8n, 32 per XCD
  const int f0 = blockIdx.x;
  const int sid = (f0 & 7) * 32 + (f0 >> 3);
  const int m0 = (sid >> 3) * 256;
  const int n0 = (sid & 7) * 128;

  const int rowA = tid >> 3;
  const int chk = (tid & 7) ^ (rowA & 7);
  const bf16* gA = A + (size_t)(m0 + rowA) * 1024 + chk * 8;
  const bf16* gB = B + (size_t)(n0 + rowA) * 1024 + chk * 8;
  char* ldsA = (char*)smem;
  char* ldsB = (char*)smem + 65536;
  const int wbase = w * 1024;

  const char* rdA = (const char*)smem + wm * 16384 + r * 128;
  const char* rdB = (const char*)smem + 65536 + (wn * 32 + r) * 128;
  const int cs0 = (qd ^ (r & 7)) * 16;
  const int cs1 = ((4 + qd) ^ (r & 7)) * 16;

  f32x4 acc[8][2];
#pragma unroll
  for (int i = 0; i < 8; ++i)
#pragma unroll
    for (int j = 0; j < 2; ++j) acc[i][j] = (f32x4){0.f, 0.f, 0.f, 0.f};
  short8 af[2][2], bfr[2][2];

  { // prologue: order B(2), A.j0(2), A.j1(2); B+A.j0 landed, A.j1 may fly
    char* sA = ldsA + wbase;
    char* sB = ldsB + wbase;
    gload_lds16(gB,          sB);
    gload_lds16(gB + 65536,  sB + 8192);
    gload_lds16(gA,          sA);
    gload_lds16(gA + 131072, sA + 16384);
    gload_lds16(gA + 65536,  sA + 8192);
    gload_lds16(gA + 196608, sA + 24576);
    BAR_VM(2);
  }

#pragma unroll 1
  for (int tt = 0; tt < 8; ++tt) {
    PJ_TILE(tt * 2, 0)
    PJ_TILE(tt * 2 + 1, 1)
  }

  // epilogue: f32 direct stores
#pragma unroll
  for (int nj = 0; nj < 2; ++nj) {
    const int col = n0 + wn * 32 + nj * 16 + r;
    const float bv = bias[col];
#pragma unroll
    for (int mi = 0; mi < 8; ++mi) {
#pragma unroll
      for (int reg = 0; reg < 4; ++reg) {
        const int row = m0 + wm * 128 + mi * 16 + qd * 4 + reg;
        out[(size_t)row * 1024 + col] = acc[mi][nj][reg] + bv;
      }
    }
  }
}

// ---------------------------------------------------------------------------
// Causal flash attention v9b (round 11, verified best): kt-parity split
// across 2 wave-groups, all-LDS-ring staging (V+K, 4-deep, post-barrier
// issue), launch_bounds(512,2) — 112 VGPR, no spill. 78.2us measured.
// ---------------------------------------------------------------------------
__global__ __launch_bounds__(512, 2) void flash9(
    const bf16* __restrict__ qk, const bf16* __restrict__ vt,
    const float* __restrict__ x, bf16* __restrict__ pb) {
  const int bh = blockIdx.x;            // 0..63 -> XCD = bh%8
  const int ip = blockIdx.y;            // 0..7
  const int b = bh >> 4, h = bh & 15;
  const int qt[4] = { 31 - ip, 23 - ip, ip + 8, ip };   // descending
  const int tid = threadIdx.x, l = tid & 63, w = tid >> 6;
  const int wg = w & 3, grp = w >> 2;   // wg: q-row group; grp: kt parity
  const int r = l & 15, quad = l >> 4;

  __shared__ __align__(16) char smem[65536];  // V ring [4][8K] | K ring [4][8K] @32K

  const bf16* Qbase = qk + (size_t)b * TSEQ * QKLD + h * HD;
  const bf16* Kbase = Qbase + 1024;
  const bf16* Vhead = vt + (size_t)bh * 64 * 2048;

  // V staging: slot tid -> d=tid>>3, chunk tid&7 (vt image rows verbatim)
  const bf16* vg = Vhead + (size_t)(tid >> 3) * 2048 + (tid & 7) * 8;
  // K staging: dest row=tid>>3, phys chunk tid&7 holds global chunk ^(row&7)
  const int krow = tid >> 3;
  const bf16* kg = Kbase + (size_t)krow * QKLD + ((tid & 7) ^ (krow & 7)) * 8;
  char* vbase = smem + w * 1024;              // + (kt&3)*8192
  char* kbase = smem + 32768 + w * 1024;      // + (kt&3)*8192

  // Q fragments (B-operand of S^T: n=lane&15=qrow, k=quad*8+j)
  short8 qf0[4], qf1[4];
#pragma unroll
  for (int t = 0; t < 4; ++t) {
    const bf16* qp = Qbase + (size_t)(qt[t] * 64 + wg * 16 + r) * QKLD + quad * 8;
    qf0[t] = *(const short8*)qp;
    qf1[t] = *(const short8*)(qp + 32);
  }

  f32x4 o[4][4], lac[4];
#pragma unroll
  for (int t = 0; t < 4; ++t) {
    lac[t] = (f32x4){0.f, 0.f, 0.f, 0.f};
#pragma unroll
    for (int nt = 0; nt < 4; ++nt) o[t][nt] = (f32x4){0.f, 0.f, 0.f, 0.f};
  }

  short4v ones4;
#pragma unroll
  for (int j = 0; j < 4; ++j) ones4[j] = (short)0x3F80;  // bf16 1.0

  short4v vf[4][4];

  const int ktmax = qt[0];
  const int qrow_l = wg * 16 + r;

  // prologue: stage V(0),V(1),K(0),K(1) into ring slots 0,1
  gload_lds16(vg,           vbase);
  gload_lds16(vg + 64,      vbase + 8192);
  gload_lds16(kg,           kbase);
  gload_lds16(kg + 131072,  kbase + 8192);    // kt stride = 64*QKLD elems

  auto tilestep = [&](int t, auto diagc, short8 (&k0)[4], short8 (&k1)[4]) {
    constexpr bool D = decltype(diagc)::value;
    f32x4 s[4];
    __builtin_amdgcn_s_setprio(1);
#pragma unroll
    for (int g = 0; g < 4; ++g) {
      f32x4 a = (f32x4){0.f, 0.f, 0.f, 0.f};
      a = MFMA32(k0[g], qf0[t], a);     // A=K, B=Q -> S^T[key][q]
      a = MFMA32(k1[g], qf1[t], a);
      s[g] = a;
    }
    __builtin_amdgcn_s_setprio(0);
    short4v pA[4];
#pragma unroll
    for (int g = 0; g < 4; ++g) {
      float p[4];
#pragma unroll
      for (int reg = 0; reg < 4; ++reg) {
        float e = EXP2(s[g][reg]);      // scale pre-folded into Q
        if (D) {
          const int kj = g * 16 + quad * 4 + reg;   // key local (kt==qt)
          if (kj > qrow_l) e = 0.f;
        }
        p[reg] = e;
      }
      union { short4v v; unsigned u[2]; } pu;
      pu.u[0] = pkbf(p[0], p[1]);
      pu.u[1] = pkbf(p[2], p[3]);
      pA[g] = pu.v;
    }
    __builtin_amdgcn_s_setprio(1);
#pragma unroll
    for (int nt = 0; nt < 4; ++nt)
#pragma unroll
      for (int g = 0; g < 4; ++g)
        o[t][nt] = MFMA16(pA[g], vf[nt][g], o[t][nt]);
#pragma unroll
    for (int g = 0; g < 4; ++g)
      lac[t] = MFMA16(pA[g], ones4, lac[t]);
    __builtin_amdgcn_s_setprio(0);
  };

  const int niter = (ktmax >> 1) + 1;
#pragma unroll 1
  for (int i = 0; i < niter; ++i) {
    const int kt = 2 * i + grp;
    const bool act = kt <= ktmax;       // group-uniform (whole waves)
    __syncthreads();                    // prev-iteration stages landed (covered)
    // prefetch next pair (tiles 2i+2, 2i+3) into slots freed at iter i-1
    const int nx0 = 2 * i + 2, nx1 = 2 * i + 3;
    if (nx0 <= ktmax) {
      gload_lds16(vg + nx0 * 64,            smem + (nx0 & 3) * 8192 + w * 1024);
      gload_lds16(kg + (size_t)nx0 * 131072, smem + 32768 + (nx0 & 3) * 8192 + w * 1024);
    }
    if (nx1 <= ktmax) {
      gload_lds16(vg + nx1 * 64,            smem + (nx1 & 3) * 8192 + w * 1024);
      gload_lds16(kg + (size_t)nx1 * 131072, smem + 32768 + (nx1 & 3) * 8192 + w * 1024);
    }
    if (act) {
      // K frags from LDS ring (XOR-swizzle read; row&7 == r&7 since g*16%8==0)
      short8 k0[4], k1[4];
      {
        const bf16* Kt = (const bf16*)(smem + 32768 + (kt & 3) * 8192);
#pragma unroll
        for (int g = 0; g < 4; ++g) {
          const bf16* kp = Kt + (g * 16 + r) * 64;
          k0[g] = *(const short8*)(kp + ((quad ^ (r & 7)) * 8));
          k1[g] = *(const short8*)(kp + (((quad + 4) ^ (r & 7)) * 8));
        }
      }
      {
        const bf16* V = (const bf16*)smem + (kt & 3) * 4096;
#pragma unroll
        for (int nt = 0; nt < 4; ++nt)
#pragma unroll
          for (int g = 0; g < 4; ++g)
            vf[nt][g] = *(const short4v*)(V + (nt * 16 + r) * 64 +
                                          (((g * 2 + (quad >> 1)) ^ (r & 7)) * 8) + (quad & 1) * 4);
      }
      if (kt == qt[0]) tilestep(0, BoolC<true>{}, k0, k1);
      else             tilestep(0, BoolC<false>{}, k0, k1);
      if (kt <= qt[1]) { if (kt == qt[1]) tilestep(1, BoolC<true>{}, k0, k1);
                         else             tilestep(1, BoolC<false>{}, k0, k1); }
      if (kt <= qt[2]) { if (kt == qt[2]) tilestep(2, BoolC<true>{}, k0, k1);
                         else             tilestep(2, BoolC<false>{}, k0, k1); }
      if (kt <= qt[3]) { if (kt == qt[3]) tilestep(3, BoolC<true>{}, k0, k1);
                         else             tilestep(3, BoolC<false>{}, k0, k1); }
    }
  }

  // ---- combine (2 rounds) + split epilogue (reuses smem[0..40K)) ----
  float* combO = (float*)smem;                 // 32 KB: [wg*64+l][8 chunks x 16B]
  float* combL = (float*)(smem + 32768);       // 8 KB : [wg*64+l][2 tiles x 16B]
  const int lb128 = (wg * 64 + l) * 32;        // float index of lane's 128B block
  const int lbl = (wg * 64 + l) * 8;

  __syncthreads();                             // all ring reads + stages complete
#pragma unroll
  for (int rnd = 0; rnd < 2; ++rnd) {
    const int wgrp = (rnd == 0) ? 1 : 0;       // writer group this round
    if (grp == wgrp) {
#pragma unroll
      for (int t2 = 0; t2 < 2; ++t2) {
        const int tt = rnd * 2 + t2;
#pragma unroll
        for (int nt = 0; nt < 4; ++nt)
          *(f32x4*)&combO[lb128 + (((t2 * 4 + nt) ^ (l & 7)) << 2)] = o[tt][nt];
        *(f32x4*)&combL[lbl + t2 * 4] = lac[tt];
      }
    }
    __syncthreads();
    if (grp != wgrp) {
#pragma unroll
      for (int t2 = 0; t2 < 2; ++t2) {
        const int tt = rnd * 2 + t2;
        const f32x4 ls = *(const f32x4*)&combL[lbl + t2 * 4];
#pragma unroll
        for (int j2 = 0; j2 < 4; ++j2) lac[tt][j2] += ls[j2];
#pragma unroll
        for (int nt = 0; nt < 4; ++nt) {
          const f32x4 ov = *(const f32x4*)&combO[lb128 + (((t2 * 4 + nt) ^ (l & 7)) << 2)];
#pragma unroll
          for (int j2 = 0; j2 < 4; ++j2) o[tt][nt][j2] += ov[j2];
        }
        // epilogue for tile tt: O /= l, +residual, bf16 store
#pragma unroll
        for (int reg = 0; reg < 4; ++reg) {
          const float inv = 1.0f / lac[tt][reg];
          const int row = qt[tt] * 64 + wg * 16 + quad * 4 + reg;
          const float* xr = x + (size_t)(b * TSEQ + row) * EMB + h * HD;
          bf16* pr = pb + (size_t)(b * TSEQ + row) * EMB + h * HD;
#pragma unroll
          for (int nt = 0; nt < 4; ++nt) {
            const int d = nt * 16 + r;
            pr[d] = __float2bfloat16(o[tt][nt][reg] * inv + xr[d]);
          }
        }
      }
    }
    if (rnd == 0) __syncthreads();             // round-1 reads done before round-2 writes
  }
}

// ---------------------------------------------------------------------------
// In-place LayerNorm over last dim (1024). One block per row, 256 thr x 4.
// ---------------------------------------------------------------------------
__global__ __launch_bounds__(256) void ln_kernel(float* __restrict__ out,
                                                 const float* __restrict__ gamma,
                                                 const float* __restrict__ beta) {
  const int row = blockIdx.x;
  const int tid = threadIdx.x;
  float* p = out + (size_t)row * EMB;
  float4 v = ((const float4*)p)[tid];
  float s = v.x + v.y + v.z + v.w;
  float ss = v.x * v.x + v.y * v.y + v.z * v.z + v.w * v.w;
#pragma unroll
  for (int m = 1; m < 64; m <<= 1) {
    s += __shfl_xor(s, m, 64);
    ss += __shfl_xor(ss, m, 64);
  }
  __shared__ float red[8];
  const int w = tid >> 6, l = tid & 63;
  if (l == 0) { red[w] = s; red[4 + w] = ss; }
  __syncthreads();
  s = red[0] + red[1] + red[2] + red[3];
  ss = red[4] + red[5] + red[6] + red[7];
  const float mu = s * (1.0f / EMB);
  const float var = ss * (1.0f / EMB) - mu * mu;
  const float rs = rsqrtf(var + 1e-6f);
  const float4 g = ((const float4*)gamma)[tid];
  const float4 bb = ((const float4*)beta)[tid];
  float4 o;
  o.x = (v.x - mu) * rs * g.x + bb.x;
  o.y = (v.y - mu) * rs * g.y + bb.y;
  o.z = (v.z - mu) * rs * g.z + bb.z;
  o.w = (v.w - mu) * rs * g.w + bb.w;
  ((float4*)p)[tid] = o;
}

// ---------------------------------------------------------------------------
extern "C" void kernel_launch(void* const* d_in, const int* in_sizes, int n_in,
                              void* d_out, int out_size, void* d_ws, size_t ws_size,
                              hipStream_t stream) {
  const float* x     = (const float*)d_in[0];
  const float* Wq    = (const float*)d_in[1];
  const float* bq    = (const float*)d_in[2];
  const float* Wk    = (const float*)d_in[3];
  const float* bk    = (const float*)d_in[4];
  const float* Wv    = (const float*)d_in[5];
  const float* bv    = (const float*)d_in[6];
  const float* Wp    = (const float*)d_in[7];
  const float* bp    = (const float*)d_in[8];
  const float* gamma = (const float*)d_in[9];
  const float* beta  = (const float*)d_in[10];
  float* out = (float*)d_out;

  // ws: xb 0-16M (reused as pb), wqkv 16-22M, wpb 22-24M, bqkv 24M(+12KB),
  // qk 25-57M (stride 2048), vt 57-73M ([b][h][d][T] swizzled)
  if (ws_size < (size_t)74 * 1024 * 1024) {
    printf("kernel_launch: ws_size %zu too small\n", ws_size);
    return;
  }
  char* ws = (char*)d_ws;
  bf16* xb    = (bf16*)ws;
  bf16* wqkv  = (bf16*)(ws + ((size_t)16 << 20));
  bf16* wpb   = (bf16*)(ws + ((size_t)22 << 20));
  float* bqkv = (float*)(ws + ((size_t)24 << 20));
  bf16* qkbuf = (bf16*)(ws + ((size_t)25 << 20));
  bf16* vtbuf = (bf16*)(ws + ((size_t)57 << 20));
  bf16* pbuf  = xb;  // xb dead after QKV GEMM

  fused_cast<<<12291, 256, 0, stream>>>(x, Wq, Wk, Wv, Wp, bq, bk, bv, xb, wqkv, wpb, bqkv);

  gemm_qkv8<<<dim3(384), dim3(512), 0, stream>>>(xb, wqkv, bqkv, qkbuf, vtbuf);

  flash9<<<dim3(64, 8), 512, 0, stream>>>(qkbuf, vtbuf, x, pbuf);

  gemm_proj8<<<dim3(256), dim3(512), 0, stream>>>(pbuf, wpb, bp, out);

  ln_kernel<<<BT, 256, 0, stream>>>(out, gamma, beta);
}